// Round 14
// baseline (975.393 us; speedup 1.0000x reference)
//
#include <hip/hip_runtime.h>
#include <hip/hip_cooperative_groups.h>

namespace cg = cooperative_groups;

#define N_NODES 100000
#define N_EDGES 400000
#define N_GRAPHS 2048
#define HID 128
#define NLAYER 4
#define TOUT 5
#define EPSV 1e-5f
#define SLOPE 0.2f
#define MAXDEG 32
#define NB 98   // (N_NODES+1023)/1024

typedef float v4f __attribute__((ext_vector_type(4)));
typedef __bf16 v8bf __attribute__((ext_vector_type(8)));

static __device__ __forceinline__ unsigned short f2bf_bits(float f){
  unsigned u = __builtin_bit_cast(unsigned, f);
  unsigned r = u + 0x7fffu + ((u >> 16) & 1u);
  return (unsigned short)(r >> 16);
}
static __device__ __forceinline__ float bfbits2f(unsigned short s){
  unsigned u = ((unsigned)s) << 16;
  return __builtin_bit_cast(float, u);
}
static __device__ __forceinline__ float bflo(unsigned u){
  return __builtin_bit_cast(float, u << 16);
}
static __device__ __forceinline__ float bfhi(unsigned u){
  return __builtin_bit_cast(float, u & 0xffff0000u);
}
static __device__ __forceinline__ float lrelu(float v){
  return v>0.f ? v : SLOPE*v;
}

// Physical bf16 layout (head-aligned pairing):
//   word u (0..63): b=u>>4, r=u&15 -> holds channels (b*32+r [lo], b*32+16+r [hi]).
//   Lane l (words 2l,2l+1) is entirely head l>>3.
//   contraction position for channel k: kp = (k>>5)*32 + (k&15)*2 + ((k>>4)&1).

// merged setup: block 0 = prep; 1..1024 = w_ext; 1025..1280 = wswz; 1281.. = zero deg/fill
__global__ void k_setup(const float* __restrict__ gat_edge_w, const float* __restrict__ att_edge,
                        const float* __restrict__ edge_w, const float* __restrict__ edge_b,
                        const float* __restrict__ gat_bias, const float* __restrict__ gamma,
                        const float* __restrict__ beta, const float* __restrict__ mean,
                        const float* __restrict__ var, const float* __restrict__ gat_lin_w,
                        const float* __restrict__ att_src, const float* __restrict__ att_dst,
                        float* __restrict__ mebuf, float* __restrict__ bnA, float* __restrict__ bnS,
                        unsigned short* __restrict__ whiE, unsigned short* __restrict__ wloE,
                        unsigned short* __restrict__ whi, unsigned short* __restrict__ wlo,
                        int* __restrict__ deg, int* __restrict__ fill){
  __shared__ float Ve[128*16];
  int bid = blockIdx.x, t = threadIdx.x;
  if(bid == 0){
    for(int i=t; i<NLAYER*HID; i+=256){
      int l_ = i>>7, pos = i&127, lane = pos>>2, j = pos&3;
      int ch = ((lane>>3)<<5) + ((lane&7)<<1) + ((j&1)<<4) + (j>>1);
      int src = l_*128 + ch;
      float A = gamma[src]*rsqrtf(var[src]+EPSV);
      bnA[i] = A;
      bnS[i] = (gat_bias[src]-mean[src])*A + beta[src];
    }
    for(int id=t; id<2048; id+=256){
      int k = id>>4, li = id&15, l = li>>2, hh = li&3;
      const float* gw = gat_edge_w + l*16384 + k*128 + hh*32;
      const float* at = att_edge + l*128 + hh*32;
      float s = 0.f;
      #pragma unroll
      for(int c=0;c<32;++c) s += gw[c]*at[c];
      Ve[k*16+li] = s;
    }
    __syncthreads();
    if(t < 48){
      int f = t>>4, li = t&15;
      float s=0.f;
      for(int k=0;k<128;++k) s += edge_w[f*128+k]*Ve[k*16+li];
      mebuf[f*16+li] = s;
    } else if (t < 64){
      int li = t-48; float s=0.f;
      for(int k=0;k<128;++k) s += edge_b[k]*Ve[k*16+li];
      mebuf[48+li] = s;
    }
  } else if(bid <= 1024){
    int wave = t>>6, lane = t&63;
    int i = (bid-1)*8 + wave*2 + (lane>>5);   // 0..8191
    int l_ = i>>11, rest = i&2047, kp = rest>>4, col = rest&15;
    int sub = lane&31;
    float val = 0.f;
    if(col < 8){
      int h_ = col&3, isdst = col>>2;
      int ch = ((kp>>5)<<5) + ((kp&1)<<4) + ((kp&31)>>1);
      const float* at = (isdst? att_dst : att_src);
      val = gat_lin_w[l_*16384 + ch*128 + h_*32 + sub] * at[l_*128 + h_*32 + sub];
    }
    val += __shfl_xor(val,1); val += __shfl_xor(val,2); val += __shfl_xor(val,4);
    val += __shfl_xor(val,8); val += __shfl_xor(val,16);
    if(sub == 0){
      unsigned short hi = f2bf_bits(val);
      unsigned short lo = f2bf_bits(val - bfbits2f(hi));
      int kb=kp>>5, quad=(kp>>3)&3, jj=kp&7, lane2=quad*16+col;
      int dst = ((l_*4+kb)*64 + lane2)*8 + jj;
      whiE[dst]=hi; wloE[dst]=lo;
    }
  } else if(bid <= 1280){
    int tg = (bid-1025)*256 + t;              // 0..65535 == dst index
    int base = tg>>9, off = tg&511;
    int l = base>>5, kb=(base>>3)&3, cg=base&7;
    int lane = off>>3, j = off&7;
    int quad = lane>>4, r = lane&15;
    int kp = kb*32 + quad*8 + j;
    int k = ((kp>>5)<<5) | ((kp&1)<<4) | ((kp&31)>>1);
    float w = gat_lin_w[l*16384 + k*128 + cg*16 + r];
    unsigned short hi = f2bf_bits(w);
    unsigned short lo = f2bf_bits(w - bfbits2f(hi));
    whi[tg]=hi; wlo[tg]=lo;
  } else {
    int tg = (bid-1281)*256 + t;
    if(tg < N_NODES){ deg[tg]=0; fill[tg]=0; }
  }
}

// one cooperative dispatch: hinit + deg count -> scan(3 phases) -> CSR fill
__global__ void __launch_bounds__(256,8)
k_csr(const float* __restrict__ x, const float* __restrict__ nw,
      const float* __restrict__ nb, unsigned* __restrict__ h16,
      const int* __restrict__ ei, const float* __restrict__ ea,
      int* __restrict__ deg, int* __restrict__ part, int* __restrict__ rowptr,
      int* __restrict__ fill, int* __restrict__ csr_src, float* __restrict__ ea_csr){
  cg::grid_group grid = cg::this_grid();
  __shared__ int s[256];
  int t = threadIdx.x;
  // phase 0: hinit (grid-stride) + deg count
  for(int bid = blockIdx.x; bid < N_NODES/4; bid += gridDim.x){
    int node = bid*4 + (t>>6);
    int c = t&63;
    int ch = ((c>>4)<<5) + (c&15);
    float a0 = nb[ch], a1 = nb[ch+16];
    #pragma unroll
    for(int f=0; f<7; ++f){
      float xv = x[node*7+f];
      a0 += xv*nw[f*HID+ch];
      a1 += xv*nw[f*HID+ch+16];
    }
    unsigned p = (unsigned)f2bf_bits(a0) | ((unsigned)f2bf_bits(a1)<<16);
    h16[(size_t)node*64 + c] = p;
  }
  for(int e = blockIdx.x*256 + t; e < N_EDGES; e += gridDim.x*256)
    atomicAdd(&deg[ei[N_EDGES+e]], 1);
  grid.sync();
  // phase 1: per-chunk sums
  for(int b = blockIdx.x; b < NB; b += gridDim.x){
    int base = b*1024 + t*4;
    int sum=0;
    #pragma unroll
    for(int j=0;j<4;++j){ int i=base+j; sum += (i<N_NODES)? deg[i]:0; }
    s[t]=sum; __syncthreads();
    for(int off=128; off>0; off>>=1){ if(t<off) s[t]+=s[t+off]; __syncthreads(); }
    if(t==0) part[b]=s[0];
  }
  grid.sync();
  // phase 2: serial scan of 98 partials
  if(blockIdx.x==0 && t==0){
    int run=0;
    for(int i=0;i<NB;++i){ int v=part[i]; part[i]=run; run+=v; }
    rowptr[N_NODES]=run;
  }
  grid.sync();
  // phase 3: per-chunk exclusive scan -> rowptr
  for(int b = blockIdx.x; b < NB; b += gridDim.x){
    int base = b*1024 + t*4;
    int v[4]; int sum=0; int pre[4];
    #pragma unroll
    for(int j=0;j<4;++j){ int i=base+j; v[j]=(i<N_NODES)?deg[i]:0; pre[j]=sum; sum+=v[j]; }
    s[t]=sum; __syncthreads();
    for(int off=1; off<256; off<<=1){
      int xv = (t>=off)? s[t-off]:0; __syncthreads();
      s[t]+=xv; __syncthreads();
    }
    int toff = (t>0)? s[t-1]:0;
    int g = part[b];
    #pragma unroll
    for(int j=0;j<4;++j){ int i=base+j; if(i<N_NODES) rowptr[i]=g+toff+pre[j]; }
  }
  grid.sync();
  // phase 4: CSR fill
  for(int e = blockIdx.x*256 + t; e < N_EDGES; e += gridDim.x*256){
    int dst = ei[N_EDGES+e];
    int pos = rowptr[dst] + atomicAdd(&fill[dst],1);
    csr_src[pos] = ei[e];
    v4f q = {ea[e*3], ea[e*3+1], ea[e*3+2], 0.f};
    ((v4f*)ea_csr)[pos] = q;
  }
}

// xh = h16 @ gat_lin_w[l]; as_/ad_ via extra 16-col MFMA tile (w_ext).
// xhb pack staged through wave-private LDS -> fully coalesced 256B row stores.
__global__ void k_gemm(const unsigned short* __restrict__ h16,
                       const unsigned short* __restrict__ whi,
                       const unsigned short* __restrict__ wlo,
                       const unsigned short* __restrict__ whiE,
                       const unsigned short* __restrict__ wloE,
                       unsigned* __restrict__ xhb, float* __restrict__ as_, float* __restrict__ ad_){
  __shared__ unsigned sxh[4][16*68];
  int wave = threadIdx.x>>6, lane = threadIdx.x&63;
  int row0 = blockIdx.x*64 + wave*16;
  if(row0 > N_NODES-16) row0 = N_NODES-16;   // clamp: duplicate work, identical values
  int q = lane>>4, r = lane&15;
  const unsigned short* hrow = h16 + (size_t)(row0 + r)*HID;
  v8bf av[4];
  #pragma unroll
  for(int kb=0;kb<4;++kb)
    av[kb] = *(const v8bf*)(hrow + kb*32 + q*8);
  v4f acc[8];
  #pragma unroll
  for(int cg=0;cg<8;++cg){
    v4f a = {0.f,0.f,0.f,0.f};
    #pragma unroll
    for(int kb=0;kb<4;++kb){
      v8bf bhi = *(const v8bf*)(whi + ((kb*8+cg)*64 + lane)*8);
      v8bf blo = *(const v8bf*)(wlo + ((kb*8+cg)*64 + lane)*8);
      a = __builtin_amdgcn_mfma_f32_16x16x32_bf16(av[kb], blo, a, 0,0,0);
      a = __builtin_amdgcn_mfma_f32_16x16x32_bf16(av[kb], bhi, a, 0,0,0);
    }
    acc[cg]=a;
  }
  v4f acc8 = {0.f,0.f,0.f,0.f};
  #pragma unroll
  for(int kb=0;kb<4;++kb){
    v8bf bhi = *(const v8bf*)(whiE + (kb*64 + lane)*8);
    v8bf blo = *(const v8bf*)(wloE + (kb*64 + lane)*8);
    acc8 = __builtin_amdgcn_mfma_f32_16x16x32_bf16(av[kb], blo, acc8, 0,0,0);
    acc8 = __builtin_amdgcn_mfma_f32_16x16x32_bf16(av[kb], bhi, acc8, 0,0,0);
  }
  // stage packed words in LDS (stride 68 words -> 2-way banking, free)
  #pragma unroll
  for(int m=0;m<4;++m){
    #pragma unroll
    for(int reg=0;reg<4;++reg){
      unsigned pack = (unsigned)f2bf_bits(acc[2*m][reg]) | ((unsigned)f2bf_bits(acc[2*m+1][reg])<<16);
      sxh[wave][(q*4+reg)*68 + m*16 + r] = pack;
    }
  }
  __syncthreads();
  // coalesced write-back: one full 256B row per instruction
  {
    int rr = lane>>4, c4 = lane&15;
    #pragma unroll
    for(int rg=0; rg<4; ++rg){
      int i = rg*4 + rr;
      uint4 v = *(const uint4*)&sxh[wave][i*68 + c4*4];
      *(uint4*)(xhb + (size_t)(row0 + i)*64 + c4*4) = v;
    }
  }
  if(r < 4){
    #pragma unroll
    for(int reg=0;reg<4;++reg)
      as_[(size_t)(row0 + q*4 + reg)*4 + r] = acc8[reg];
  } else if(r < 8){
    #pragma unroll
    for(int reg=0;reg<4;++reg)
      ad_[(size_t)(row0 + q*4 + reg)*4 + (r-4)] = acc8[reg];
  }
}

// wave-per-node. Phase A: parallel softmax anchored at self-logit; deg<=16 fast
// path. Phase B: half-wave uint2 gather (lane's 4 channels all in head l>>3).
// Epilogue: permuted folded BN + relu + bf16 residual; writes h16.
__global__ void k_aggr(const unsigned* __restrict__ xhb, const float* __restrict__ as_,
    const float* __restrict__ ad_, const float* __restrict__ ea_csr,
    const float* __restrict__ mebuf,
    const int* __restrict__ rowptr, const int* __restrict__ csr_src,
    const float* __restrict__ bnA_l, const float* __restrict__ bnS_l,
    unsigned* __restrict__ h16, int layer){
  __shared__ float lds_coef[4][MAXDEG*4];
  __shared__ int   lds_src[4][MAXDEG];
  int w = threadIdx.x>>6, lane = threadIdx.x&63;
  int node = blockIdx.x*4 + w;
  if(node >= N_NODES) return;
  int s = rowptr[node], e = rowptr[node+1];
  int deg = e - s;
  int l = lane&31, half = lane>>5, hh2 = l>>3;
  const uint2* xrow = (const uint2*)xhb;
  float a0,a1,a2,a3;

  if(deg <= MAXDEG){
    int eidx = lane>>2, h = lane&3;
    int li = layer*4+h;
    float mec0=mebuf[li], mec1=mebuf[16+li], mec2=mebuf[32+li], meb=mebuf[48+li];
    float ad_h = ad_[node*4+h];
    int j0 = eidx;
    float t0 = 0.f, g0 = 0.f;
    int s0 = node;
    bool v0 = (j0 < deg);
    if(v0){
      s0 = csr_src[s+j0];
      v4f qq = ((const v4f*)ea_csr)[s+j0];
      t0 = qq.x*mec0 + qq.y*mec1 + qq.z*mec2;
      g0 = lrelu(as_[s0*4+h] + ad_h + t0 + meb);
    }
    float ts, ds, inv;
    if(deg <= 16){
      ts = t0;
      ts += __shfl_xor(ts,4); ts += __shfl_xor(ts,8);
      ts += __shfl_xor(ts,16); ts += __shfl_xor(ts,32);
      float lt = (deg>0) ? ts/(float)deg + meb : 0.f;
      float al = lrelu(as_[node*4+h] + ad_h + lt);
      float e0 = v0 ? __expf(g0-al) : 0.f;
      ds = e0;
      ds += __shfl_xor(ds,4); ds += __shfl_xor(ds,8);
      ds += __shfl_xor(ds,16); ds += __shfl_xor(ds,32);
      inv = 1.f/(ds+1.f);
      lds_src[w][j0] = s0;
      lds_coef[w][j0*4+h] = e0*inv;
    } else {
      int j1 = 16+eidx;
      float t1 = 0.f, g1 = 0.f;
      int s1 = node;
      bool v1 = (j1 < deg);
      if(v1){
        s1 = csr_src[s+j1];
        v4f qq = ((const v4f*)ea_csr)[s+j1];
        t1 = qq.x*mec0 + qq.y*mec1 + qq.z*mec2;
        g1 = lrelu(as_[s1*4+h] + ad_h + t1 + meb);
      }
      ts = t0+t1;
      ts += __shfl_xor(ts,4); ts += __shfl_xor(ts,8);
      ts += __shfl_xor(ts,16); ts += __shfl_xor(ts,32);
      float lt = ts/(float)deg + meb;
      float al = lrelu(as_[node*4+h] + ad_h + lt);
      float e0 = v0 ? __expf(g0-al) : 0.f;
      float e1 = v1 ? __expf(g1-al) : 0.f;
      ds = e0+e1;
      ds += __shfl_xor(ds,4); ds += __shfl_xor(ds,8);
      ds += __shfl_xor(ds,16); ds += __shfl_xor(ds,32);
      inv = 1.f/(ds+1.f);
      if(h==0){ lds_src[w][j0]=s0; lds_src[w][j1]=s1; }
      lds_coef[w][j0*4+h] = e0*inv;
      lds_coef[w][j1*4+h] = e1*inv;
    }
    // ---- phase B ----
    float cs4 = __shfl(inv, hh2);
    uint2 su = xrow[(size_t)node*32 + l];
    int pdeg = (deg+3)&~3;
    a0=a1=a2=a3=0.f;
    for(int j=0;j<pdeg;j+=4){
      float ca = lds_coef[w][(j+half)*4+hh2];
      float cb = lds_coef[w][(j+2+half)*4+hh2];
      int sa = lds_src[w][j+half], sb = lds_src[w][j+2+half];
      uint2 ua = xrow[(size_t)sa*32+l];
      uint2 ub = xrow[(size_t)sb*32+l];
      a0 += ca*bflo(ua.x) + cb*bflo(ub.x);
      a1 += ca*bfhi(ua.x) + cb*bfhi(ub.x);
      a2 += ca*bflo(ua.y) + cb*bflo(ub.y);
      a3 += ca*bfhi(ua.y) + cb*bfhi(ub.y);
    }
    a0 += __shfl_xor(a0,32); a1 += __shfl_xor(a1,32);
    a2 += __shfl_xor(a2,32); a3 += __shfl_xor(a3,32);
    a0 += cs4*bflo(su.x); a1 += cs4*bfhi(su.x);
    a2 += cs4*bflo(su.y); a3 += cs4*bfhi(su.y);
  } else {
    int li = layer*4+hh2;
    float mec0=mebuf[li], mec1=mebuf[16+li], mec2=mebuf[32+li], meb=mebuf[48+li];
    float adv = ad_[node*4+hh2];
    float ts = 0.f;
    for(int j=s;j<e;++j){
      v4f qq = ((const v4f*)ea_csr)[j];
      ts += qq.x*mec0 + qq.y*mec1 + qq.z*mec2;
    }
    float al = lrelu(as_[node*4+hh2] + adv + ts/(float)deg + meb);
    float m = al, d = 1.f;
    uint2 su = xrow[(size_t)node*32 + l];
    float c0=bflo(su.x),c1=bfhi(su.x),c2=bflo(su.y),c3=bfhi(su.y);
    for(int j=s;j<e;++j){
      int sr = csr_src[j];
      v4f qq = ((const v4f*)ea_csr)[j];
      float b = lrelu(as_[sr*4+hh2] + adv + qq.x*mec0+qq.y*mec1+qq.z*mec2+meb);
      uint2 uv = xrow[(size_t)sr*32 + l];
      float nm = fmaxf(m,b);
      float sc = __expf(m-nm), eb = __expf(b-nm);
      d = d*sc + eb;
      c0 = c0*sc + eb*bflo(uv.x); c1 = c1*sc + eb*bfhi(uv.x);
      c2 = c2*sc + eb*bflo(uv.y); c3 = c3*sc + eb*bfhi(uv.y);
      m = nm;
    }
    float inv2 = 1.f/d;
    a0=c0*inv2; a1=c1*inv2; a2=c2*inv2; a3=c3*inv2;
  }

  if(half==0){
    const v4f* A4 = (const v4f*)bnA_l;
    const v4f* S4 = (const v4f*)bnS_l;
    v4f A = A4[l], S = S4[l];
    uint2 hr = ((const uint2*)h16)[(size_t)node*32 + l];
    float o0 = fmaxf(a0*A.x+S.x, 0.f) + bflo(hr.x);
    float o1 = fmaxf(a1*A.y+S.y, 0.f) + bfhi(hr.x);
    float o2 = fmaxf(a2*A.z+S.z, 0.f) + bflo(hr.y);
    float o3 = fmaxf(a3*A.w+S.w, 0.f) + bfhi(hr.y);
    uint2 p;
    p.x = (unsigned)f2bf_bits(o0) | ((unsigned)f2bf_bits(o1)<<16);
    p.y = (unsigned)f2bf_bits(o2) | ((unsigned)f2bf_bits(o3)<<16);
    ((uint2*)h16)[(size_t)node*32 + l] = p;
  }
}

// fused pool + head
__global__ void k_tail(const unsigned* __restrict__ h16, const int* __restrict__ batch,
   const float* __restrict__ gf,
   const float* __restrict__ gc_w, const float* __restrict__ gc_b,
   const float* __restrict__ gf1_w, const float* __restrict__ gf1_b,
   const float* __restrict__ gf2_w, const float* __restrict__ gf2_b,
   const float* __restrict__ p1_w, const float* __restrict__ p1_b,
   const float* __restrict__ p2_w, const float* __restrict__ p2_b,
   const float* __restrict__ p3_w, const float* __restrict__ p3_b,
   float* __restrict__ out){
  __shared__ float sg[384];
  __shared__ int sb[2];
  __shared__ float comb[192];
  __shared__ float hid1[64];
  __shared__ float r1[128];
  __shared__ float r2[64];
  int g = blockIdx.x, t = threadIdx.x;
  if(t < 2){
    int target = g + t;
    int lo=0, hi=N_NODES;
    while(lo<hi){ int mid=(lo+hi)>>1; if(batch[mid] < target) lo=mid+1; else hi=mid; }
    sb[t]=lo;
  }
  __syncthreads();
  {
    int s = sb[0], e = sb[1];
    int u = ((t>>5)<<4) + (t&15);
    int hiflag = (t>>4)&1;
    float sum=0.f, mx=-3.4e38f;
    for(int i=s;i<e;++i){
      unsigned uv = h16[(size_t)i*64 + u];
      float v = hiflag ? bfhi(uv) : bflo(uv);
      sum+=v; mx=fmaxf(mx,v);
    }
    int cnt = e-s;
    float meanv = sum / (float)(cnt>1?cnt:1);
    if(cnt==0) mx=0.f;
    sg[t] = meanv;
    sg[128+t] = mx;
    sg[256+t] = sum;
  }
  if(t<64){
    float a = gf1_b[t];
    #pragma unroll
    for(int i=0;i<10;++i) a += gf[g*10+i]*gf1_w[i*64+t];
    hid1[t] = fmaxf(a,0.f);
  }
  __syncthreads();
  if(t<64){
    float a = gf2_b[t];
    for(int k=0;k<64;++k) a += hid1[k]*gf2_w[k*64+t];
    comb[128+t] = a;
  }
  {
    float a = gc_b[t];
    for(int k=0;k<384;++k) a += sg[k]*gc_w[k*128+t];
    comb[t] = fmaxf(a,0.f);
  }
  __syncthreads();
  {
    float a = p1_b[t];
    for(int k=0;k<192;++k) a += comb[k]*p1_w[k*128+t];
    r1[t] = fmaxf(a,0.f);
  }
  __syncthreads();
  if(t<64){
    float a = p2_b[t];
    for(int k=0;k<128;++k) a += r1[k]*p2_w[k*64+t];
    r2[t] = fmaxf(a,0.f);
  }
  __syncthreads();
  if(t<TOUT){
    float a = p3_b[t];
    for(int k=0;k<64;++k) a += r2[k]*p3_w[k*TOUT+t];
    out[g*TOUT+t] = a;
  }
}

extern "C" void kernel_launch(void* const* d_in, const int* in_sizes, int n_in,
                              void* d_out, int out_size, void* d_ws, size_t ws_size,
                              hipStream_t stream){
  (void)in_sizes; (void)n_in; (void)out_size; (void)ws_size;
  const float* x        = (const float*)d_in[0];
  const int*   ei       = (const int*)d_in[1];
  const float* ea       = (const float*)d_in[2];
  const int*   batch    = (const int*)d_in[3];
  const float* gfin     = (const float*)d_in[4];
  const float* node_w   = (const float*)d_in[5];
  const float* node_b   = (const float*)d_in[6];
  const float* edge_w   = (const float*)d_in[7];
  const float* edge_b   = (const float*)d_in[8];
  const float* gat_lin_w  = (const float*)d_in[9];
  const float* gat_edge_w = (const float*)d_in[10];
  const float* att_src  = (const float*)d_in[11];
  const float* att_dst  = (const float*)d_in[12];
  const float* att_edge = (const float*)d_in[13];
  const float* gat_bias = (const float*)d_in[14];
  const float* bn_gamma = (const float*)d_in[15];
  const float* bn_beta  = (const float*)d_in[16];
  const float* bn_mean  = (const float*)d_in[17];
  const float* bn_var   = (const float*)d_in[18];
  const float* gc_w = (const float*)d_in[19];
  const float* gc_b = (const float*)d_in[20];
  const float* gf1_w = (const float*)d_in[21];
  const float* gf1_b = (const float*)d_in[22];
  const float* gf2_w = (const float*)d_in[23];
  const float* gf2_b = (const float*)d_in[24];
  const float* p1_w = (const float*)d_in[25];
  const float* p1_b = (const float*)d_in[26];
  const float* p2_w = (const float*)d_in[27];
  const float* p2_b = (const float*)d_in[28];
  const float* p3_w = (const float*)d_in[29];
  const float* p3_b = (const float*)d_in[30];
  float* out = (float*)d_out;

  char* w = (char*)d_ws;
  size_t o = 0;
  auto carve = [&](size_t bytes)->char*{
    char* p = w + o; o += (bytes + 255) & ~(size_t)255; return p;
  };
  unsigned* xhb = (unsigned*)carve((size_t)N_NODES*64*4);
  unsigned* h16 = (unsigned*)carve((size_t)N_NODES*64*4);
  float* ea_csr = (float*)carve((size_t)N_EDGES*4*4);
  float* as_    = (float*)carve((size_t)N_NODES*4*4);
  float* ad_    = (float*)carve((size_t)N_NODES*4*4);
  int* deg      = (int*)carve((size_t)N_NODES*4);
  int* rowptr   = (int*)carve((size_t)(N_NODES+1)*4);
  int* fill     = (int*)carve((size_t)N_NODES*4);
  int* csr_src  = (int*)carve((size_t)N_EDGES*4);
  int* part     = (int*)carve(1024*4);
  float* mebuf  = (float*)carve(64*4);
  float* bnA    = (float*)carve((size_t)NLAYER*HID*4);
  float* bnS    = (float*)carve((size_t)NLAYER*HID*4);
  unsigned short* whi = (unsigned short*)carve(65536*2);
  unsigned short* wlo = (unsigned short*)carve(65536*2);
  unsigned short* whiE = (unsigned short*)carve(8192*2);
  unsigned short* wloE = (unsigned short*)carve(8192*2);

  // setup: prep + w_ext + wswz + zero(deg,fill)   [replaces 2 memsets]
  int zb = (N_NODES+255)/256;
  k_setup<<<1 + 1024 + 256 + zb, 256, 0, stream>>>(gat_edge_w, att_edge, edge_w, edge_b,
        gat_bias, bn_gamma, bn_beta, bn_mean, bn_var,
        gat_lin_w, att_src, att_dst, mebuf, bnA, bnS, whiE, wloE, whi, wlo, deg, fill);

  // one cooperative dispatch: hinit+deg -> scan -> fill
  {
    void* args[] = { (void*)&x, (void*)&node_w, (void*)&node_b, (void*)&h16,
                     (void*)&ei, (void*)&ea, (void*)&deg, (void*)&part, (void*)&rowptr,
                     (void*)&fill, (void*)&csr_src, (void*)&ea_csr };
    (void)hipLaunchCooperativeKernel(reinterpret_cast<void*>(k_csr),
                                     dim3(1024), dim3(256), args, 0, stream);
  }

  for(int l=0;l<NLAYER;++l){
    k_gemm<<<(N_NODES+63)/64,256,0,stream>>>((const unsigned short*)h16,
        whi + l*16384, wlo + l*16384, whiE + l*2048, wloE + l*2048,
        xhb, as_, ad_);
    k_aggr<<<(N_NODES+3)/4,256,0,stream>>>(xhb, as_, ad_, ea_csr, mebuf,
        rowptr, csr_src, bnA + l*128, bnS + l*128, h16, l);
  }

  k_tail<<<N_GRAPHS,128,0,stream>>>(h16, batch, gfin, gc_w, gc_b, gf1_w, gf1_b,
        gf2_w, gf2_b, p1_w, p1_b, p2_w, p2_b, p3_w, p3_b, out);
}

// Round 15
// 555.382 us; speedup vs baseline: 1.7563x; 1.7563x over previous
//
#include <hip/hip_runtime.h>

#define N_NODES 100000
#define N_EDGES 400000
#define N_GRAPHS 2048
#define HID 128
#define NLAYER 4
#define TOUT 5
#define EPSV 1e-5f
#define SLOPE 0.2f
#define MAXDEG 32

typedef float v4f __attribute__((ext_vector_type(4)));
typedef __bf16 v8bf __attribute__((ext_vector_type(8)));

static __device__ __forceinline__ unsigned short f2bf_bits(float f){
  unsigned u = __builtin_bit_cast(unsigned, f);
  unsigned r = u + 0x7fffu + ((u >> 16) & 1u);
  return (unsigned short)(r >> 16);
}
static __device__ __forceinline__ float bfbits2f(unsigned short s){
  unsigned u = ((unsigned)s) << 16;
  return __builtin_bit_cast(float, u);
}
static __device__ __forceinline__ float bflo(unsigned u){
  return __builtin_bit_cast(float, u << 16);
}
static __device__ __forceinline__ float bfhi(unsigned u){
  return __builtin_bit_cast(float, u & 0xffff0000u);
}
static __device__ __forceinline__ float lrelu(float v){
  return v>0.f ? v : SLOPE*v;
}

// Physical bf16 layout (head-aligned pairing):
//   word u (0..63): b=u>>4, r=u&15 -> holds channels (b*32+r [lo], b*32+16+r [hi]).
//   Lane l (words 2l,2l+1) is entirely head l>>3.
//   contraction position for channel k: kp = (k>>5)*32 + (k&15)*2 + ((k>>4)&1).

// merged setup: block 0 = prep; 1..1024 = w_ext; 1025..1280 = wswz; 1281.. = zero deg/fill
__global__ void k_setup(const float* __restrict__ gat_edge_w, const float* __restrict__ att_edge,
                        const float* __restrict__ edge_w, const float* __restrict__ edge_b,
                        const float* __restrict__ gat_bias, const float* __restrict__ gamma,
                        const float* __restrict__ beta, const float* __restrict__ mean,
                        const float* __restrict__ var, const float* __restrict__ gat_lin_w,
                        const float* __restrict__ att_src, const float* __restrict__ att_dst,
                        float* __restrict__ mebuf, float* __restrict__ bnA, float* __restrict__ bnS,
                        unsigned short* __restrict__ whiE, unsigned short* __restrict__ wloE,
                        unsigned short* __restrict__ whi, unsigned short* __restrict__ wlo,
                        int* __restrict__ deg, int* __restrict__ fill){
  __shared__ float Ve[128*16];
  int bid = blockIdx.x, t = threadIdx.x;
  if(bid == 0){
    for(int i=t; i<NLAYER*HID; i+=256){
      int l_ = i>>7, pos = i&127, lane = pos>>2, j = pos&3;
      int ch = ((lane>>3)<<5) + ((lane&7)<<1) + ((j&1)<<4) + (j>>1);
      int src = l_*128 + ch;
      float A = gamma[src]*rsqrtf(var[src]+EPSV);
      bnA[i] = A;
      bnS[i] = (gat_bias[src]-mean[src])*A + beta[src];
    }
    for(int id=t; id<2048; id+=256){
      int k = id>>4, li = id&15, l = li>>2, hh = li&3;
      const float* gw = gat_edge_w + l*16384 + k*128 + hh*32;
      const float* at = att_edge + l*128 + hh*32;
      float s = 0.f;
      #pragma unroll
      for(int c=0;c<32;++c) s += gw[c]*at[c];
      Ve[k*16+li] = s;
    }
    __syncthreads();
    if(t < 48){
      int f = t>>4, li = t&15;
      float s=0.f;
      for(int k=0;k<128;++k) s += edge_w[f*128+k]*Ve[k*16+li];
      mebuf[f*16+li] = s;
    } else if (t < 64){
      int li = t-48; float s=0.f;
      for(int k=0;k<128;++k) s += edge_b[k]*Ve[k*16+li];
      mebuf[48+li] = s;
    }
  } else if(bid <= 1024){
    int wave = t>>6, lane = t&63;
    int i = (bid-1)*8 + wave*2 + (lane>>5);   // 0..8191
    int l_ = i>>11, rest = i&2047, kp = rest>>4, col = rest&15;
    int sub = lane&31;
    float val = 0.f;
    if(col < 8){
      int h_ = col&3, isdst = col>>2;
      int ch = ((kp>>5)<<5) + ((kp&1)<<4) + ((kp&31)>>1);
      const float* at = (isdst? att_dst : att_src);
      val = gat_lin_w[l_*16384 + ch*128 + h_*32 + sub] * at[l_*128 + h_*32 + sub];
    }
    val += __shfl_xor(val,1); val += __shfl_xor(val,2); val += __shfl_xor(val,4);
    val += __shfl_xor(val,8); val += __shfl_xor(val,16);
    if(sub == 0){
      unsigned short hi = f2bf_bits(val);
      unsigned short lo = f2bf_bits(val - bfbits2f(hi));
      int kb=kp>>5, quad=(kp>>3)&3, jj=kp&7, lane2=quad*16+col;
      int dst = ((l_*4+kb)*64 + lane2)*8 + jj;
      whiE[dst]=hi; wloE[dst]=lo;
    }
  } else if(bid <= 1280){
    int tg = (bid-1025)*256 + t;              // 0..65535 == dst index
    int base = tg>>9, off = tg&511;
    int l = base>>5, kb=(base>>3)&3, cg=base&7;
    int lane = off>>3, j = off&7;
    int quad = lane>>4, r = lane&15;
    int kp = kb*32 + quad*8 + j;
    int k = ((kp>>5)<<5) | ((kp&1)<<4) | ((kp&31)>>1);
    float w = gat_lin_w[l*16384 + k*128 + cg*16 + r];
    unsigned short hi = f2bf_bits(w);
    unsigned short lo = f2bf_bits(w - bfbits2f(hi));
    whi[tg]=hi; wlo[tg]=lo;
  } else {
    int tg = (bid-1281)*256 + t;
    if(tg < N_NODES){ deg[tg]=0; fill[tg]=0; }
  }
}

// merged init: blocks 0..24999 = hinit; 25000.. = deg
__global__ void k_init(const float* __restrict__ x, const float* __restrict__ nw,
                       const float* __restrict__ nb, unsigned* __restrict__ h16,
                       const int* __restrict__ ei, int* __restrict__ deg){
  int bid = blockIdx.x, t = threadIdx.x;
  if(bid < N_NODES/4){
    int node = bid*4 + (t>>6);
    int c = t&63;
    int ch = ((c>>4)<<5) + (c&15);
    float a0 = nb[ch], a1 = nb[ch+16];
    #pragma unroll
    for(int f=0; f<7; ++f){
      float xv = x[node*7+f];
      a0 += xv*nw[f*HID+ch];
      a1 += xv*nw[f*HID+ch+16];
    }
    unsigned p = (unsigned)f2bf_bits(a0) | ((unsigned)f2bf_bits(a1)<<16);
    h16[(size_t)node*64 + c] = p;
  } else {
    int e = (bid - N_NODES/4)*256 + t;
    if(e < N_EDGES) atomicAdd(&deg[ei[N_EDGES+e]], 1);
  }
}

// exclusive scan of deg -> rowptr (3 phases, chunk=1024)
__global__ void k_scan1(const int* __restrict__ deg, int* __restrict__ part){
  __shared__ int s[256];
  int t=threadIdx.x; int base = blockIdx.x*1024 + t*4;
  int sum=0;
  #pragma unroll
  for(int j=0;j<4;++j){ int i=base+j; sum += (i<N_NODES)? deg[i]:0; }
  s[t]=sum; __syncthreads();
  for(int off=128; off>0; off>>=1){ if(t<off) s[t]+=s[t+off]; __syncthreads(); }
  if(t==0) part[blockIdx.x]=s[0];
}
__global__ void k_scan2(int* __restrict__ part, int* __restrict__ rowptr, int nb){
  if(threadIdx.x==0 && blockIdx.x==0){
    int run=0;
    for(int i=0;i<nb;++i){ int v=part[i]; part[i]=run; run+=v; }
    rowptr[N_NODES]=run;
  }
}
__global__ void k_scan3(const int* __restrict__ deg, const int* __restrict__ part, int* __restrict__ rowptr){
  __shared__ int s[256];
  int t=threadIdx.x; int base = blockIdx.x*1024 + t*4;
  int v[4]; int sum=0; int pre[4];
  #pragma unroll
  for(int j=0;j<4;++j){ int i=base+j; v[j]=(i<N_NODES)?deg[i]:0; pre[j]=sum; sum+=v[j]; }
  s[t]=sum; __syncthreads();
  for(int off=1; off<256; off<<=1){
    int xv = (t>=off)? s[t-off]:0; __syncthreads();
    s[t]+=xv; __syncthreads();
  }
  int toff = (t>0)? s[t-1]:0;
  int g = part[blockIdx.x];
  #pragma unroll
  for(int j=0;j<4;++j){ int i=base+j; if(i<N_NODES) rowptr[i]=g+toff+pre[j]; }
}

// build CSR: src ids + edge_attr (padded to float4)
__global__ void k_fill(const int* __restrict__ ei, const float* __restrict__ ea,
                       const int* __restrict__ rowptr, int* __restrict__ fill,
                       int* __restrict__ csr_src, float* __restrict__ ea_csr){
  int e = blockIdx.x*256+threadIdx.x;
  if(e>=N_EDGES) return;
  int dst = ei[N_EDGES+e];
  int pos = rowptr[dst] + atomicAdd(&fill[dst],1);
  csr_src[pos] = ei[e];
  v4f q = {ea[e*3], ea[e*3+1], ea[e*3+2], 0.f};
  ((v4f*)ea_csr)[pos] = q;
}

// xh = h16 @ gat_lin_w[l]; as_/ad_ via extra 16-col MFMA tile (w_ext).
// xhb pack staged through wave-private LDS -> fully coalesced 256B row stores.
__global__ void k_gemm(const unsigned short* __restrict__ h16,
                       const unsigned short* __restrict__ whi,
                       const unsigned short* __restrict__ wlo,
                       const unsigned short* __restrict__ whiE,
                       const unsigned short* __restrict__ wloE,
                       unsigned* __restrict__ xhb, float* __restrict__ as_, float* __restrict__ ad_){
  __shared__ unsigned sxh[4][16*68];
  int wave = threadIdx.x>>6, lane = threadIdx.x&63;
  int row0 = blockIdx.x*64 + wave*16;
  if(row0 > N_NODES-16) row0 = N_NODES-16;   // clamp: duplicate work, identical values
  int q = lane>>4, r = lane&15;
  const unsigned short* hrow = h16 + (size_t)(row0 + r)*HID;
  v8bf av[4];
  #pragma unroll
  for(int kb=0;kb<4;++kb)
    av[kb] = *(const v8bf*)(hrow + kb*32 + q*8);
  v4f acc[8];
  #pragma unroll
  for(int cg=0;cg<8;++cg){
    v4f a = {0.f,0.f,0.f,0.f};
    #pragma unroll
    for(int kb=0;kb<4;++kb){
      v8bf bhi = *(const v8bf*)(whi + ((kb*8+cg)*64 + lane)*8);
      v8bf blo = *(const v8bf*)(wlo + ((kb*8+cg)*64 + lane)*8);
      a = __builtin_amdgcn_mfma_f32_16x16x32_bf16(av[kb], blo, a, 0,0,0);
      a = __builtin_amdgcn_mfma_f32_16x16x32_bf16(av[kb], bhi, a, 0,0,0);
    }
    acc[cg]=a;
  }
  v4f acc8 = {0.f,0.f,0.f,0.f};
  #pragma unroll
  for(int kb=0;kb<4;++kb){
    v8bf bhi = *(const v8bf*)(whiE + (kb*64 + lane)*8);
    v8bf blo = *(const v8bf*)(wloE + (kb*64 + lane)*8);
    acc8 = __builtin_amdgcn_mfma_f32_16x16x32_bf16(av[kb], blo, acc8, 0,0,0);
    acc8 = __builtin_amdgcn_mfma_f32_16x16x32_bf16(av[kb], bhi, acc8, 0,0,0);
  }
  // stage packed words in LDS (stride 68 words -> 2-way banking, free)
  #pragma unroll
  for(int m=0;m<4;++m){
    #pragma unroll
    for(int reg=0;reg<4;++reg){
      unsigned pack = (unsigned)f2bf_bits(acc[2*m][reg]) | ((unsigned)f2bf_bits(acc[2*m+1][reg])<<16);
      sxh[wave][(q*4+reg)*68 + m*16 + r] = pack;
    }
  }
  __syncthreads();
  // coalesced write-back: one full 256B row per instruction
  {
    int rr = lane>>4, c4 = lane&15;
    #pragma unroll
    for(int rg=0; rg<4; ++rg){
      int i = rg*4 + rr;
      uint4 v = *(const uint4*)&sxh[wave][i*68 + c4*4];
      *(uint4*)(xhb + (size_t)(row0 + i)*64 + c4*4) = v;
    }
  }
  if(r < 4){
    #pragma unroll
    for(int reg=0;reg<4;++reg)
      as_[(size_t)(row0 + q*4 + reg)*4 + r] = acc8[reg];
  } else if(r < 8){
    #pragma unroll
    for(int reg=0;reg<4;++reg)
      ad_[(size_t)(row0 + q*4 + reg)*4 + (r-4)] = acc8[reg];
  }
}

// wave-per-node. Phase A: parallel softmax anchored at self-logit; deg<=16 fast
// path. Phase B: half-wave uint2 gather (lane's 4 channels all in head l>>3).
// Epilogue: permuted folded BN + relu + bf16 residual; writes h16.
__global__ void k_aggr(const unsigned* __restrict__ xhb, const float* __restrict__ as_,
    const float* __restrict__ ad_, const float* __restrict__ ea_csr,
    const float* __restrict__ mebuf,
    const int* __restrict__ rowptr, const int* __restrict__ csr_src,
    const float* __restrict__ bnA_l, const float* __restrict__ bnS_l,
    unsigned* __restrict__ h16, int layer){
  __shared__ float lds_coef[4][MAXDEG*4];
  __shared__ int   lds_src[4][MAXDEG];
  int w = threadIdx.x>>6, lane = threadIdx.x&63;
  int node = blockIdx.x*4 + w;
  if(node >= N_NODES) return;
  int s = rowptr[node], e = rowptr[node+1];
  int deg = e - s;
  int l = lane&31, half = lane>>5, hh2 = l>>3;
  const uint2* xrow = (const uint2*)xhb;
  float a0,a1,a2,a3;

  if(deg <= MAXDEG){
    int eidx = lane>>2, h = lane&3;
    int li = layer*4+h;
    float mec0=mebuf[li], mec1=mebuf[16+li], mec2=mebuf[32+li], meb=mebuf[48+li];
    float ad_h = ad_[node*4+h];
    int j0 = eidx;
    float t0 = 0.f, g0 = 0.f;
    int s0 = node;
    bool v0 = (j0 < deg);
    if(v0){
      s0 = csr_src[s+j0];
      v4f qq = ((const v4f*)ea_csr)[s+j0];
      t0 = qq.x*mec0 + qq.y*mec1 + qq.z*mec2;
      g0 = lrelu(as_[s0*4+h] + ad_h + t0 + meb);
    }
    float ts, ds, inv;
    if(deg <= 16){
      ts = t0;
      ts += __shfl_xor(ts,4); ts += __shfl_xor(ts,8);
      ts += __shfl_xor(ts,16); ts += __shfl_xor(ts,32);
      float lt = (deg>0) ? ts/(float)deg + meb : 0.f;
      float al = lrelu(as_[node*4+h] + ad_h + lt);
      float e0 = v0 ? __expf(g0-al) : 0.f;
      ds = e0;
      ds += __shfl_xor(ds,4); ds += __shfl_xor(ds,8);
      ds += __shfl_xor(ds,16); ds += __shfl_xor(ds,32);
      inv = 1.f/(ds+1.f);
      lds_src[w][j0] = s0;
      lds_coef[w][j0*4+h] = e0*inv;
    } else {
      int j1 = 16+eidx;
      float t1 = 0.f, g1 = 0.f;
      int s1 = node;
      bool v1 = (j1 < deg);
      if(v1){
        s1 = csr_src[s+j1];
        v4f qq = ((const v4f*)ea_csr)[s+j1];
        t1 = qq.x*mec0 + qq.y*mec1 + qq.z*mec2;
        g1 = lrelu(as_[s1*4+h] + ad_h + t1 + meb);
      }
      ts = t0+t1;
      ts += __shfl_xor(ts,4); ts += __shfl_xor(ts,8);
      ts += __shfl_xor(ts,16); ts += __shfl_xor(ts,32);
      float lt = ts/(float)deg + meb;
      float al = lrelu(as_[node*4+h] + ad_h + lt);
      float e0 = v0 ? __expf(g0-al) : 0.f;
      float e1 = v1 ? __expf(g1-al) : 0.f;
      ds = e0+e1;
      ds += __shfl_xor(ds,4); ds += __shfl_xor(ds,8);
      ds += __shfl_xor(ds,16); ds += __shfl_xor(ds,32);
      inv = 1.f/(ds+1.f);
      if(h==0){ lds_src[w][j0]=s0; lds_src[w][j1]=s1; }
      lds_coef[w][j0*4+h] = e0*inv;
      lds_coef[w][j1*4+h] = e1*inv;
    }
    // ---- phase B ----
    float cs4 = __shfl(inv, hh2);
    uint2 su = xrow[(size_t)node*32 + l];
    int pdeg = (deg+3)&~3;
    a0=a1=a2=a3=0.f;
    for(int j=0;j<pdeg;j+=4){
      float ca = lds_coef[w][(j+half)*4+hh2];
      float cb = lds_coef[w][(j+2+half)*4+hh2];
      int sa = lds_src[w][j+half], sb = lds_src[w][j+2+half];
      uint2 ua = xrow[(size_t)sa*32+l];
      uint2 ub = xrow[(size_t)sb*32+l];
      a0 += ca*bflo(ua.x) + cb*bflo(ub.x);
      a1 += ca*bfhi(ua.x) + cb*bfhi(ub.x);
      a2 += ca*bflo(ua.y) + cb*bflo(ub.y);
      a3 += ca*bfhi(ua.y) + cb*bfhi(ub.y);
    }
    a0 += __shfl_xor(a0,32); a1 += __shfl_xor(a1,32);
    a2 += __shfl_xor(a2,32); a3 += __shfl_xor(a3,32);
    a0 += cs4*bflo(su.x); a1 += cs4*bfhi(su.x);
    a2 += cs4*bflo(su.y); a3 += cs4*bfhi(su.y);
  } else {
    int li = layer*4+hh2;
    float mec0=mebuf[li], mec1=mebuf[16+li], mec2=mebuf[32+li], meb=mebuf[48+li];
    float adv = ad_[node*4+hh2];
    float ts = 0.f;
    for(int j=s;j<e;++j){
      v4f qq = ((const v4f*)ea_csr)[j];
      ts += qq.x*mec0 + qq.y*mec1 + qq.z*mec2;
    }
    float al = lrelu(as_[node*4+hh2] + adv + ts/(float)deg + meb);
    float m = al, d = 1.f;
    uint2 su = xrow[(size_t)node*32 + l];
    float c0=bflo(su.x),c1=bfhi(su.x),c2=bflo(su.y),c3=bfhi(su.y);
    for(int j=s;j<e;++j){
      int sr = csr_src[j];
      v4f qq = ((const v4f*)ea_csr)[j];
      float b = lrelu(as_[sr*4+hh2] + adv + qq.x*mec0+qq.y*mec1+qq.z*mec2+meb);
      uint2 uv = xrow[(size_t)sr*32 + l];
      float nm = fmaxf(m,b);
      float sc = __expf(m-nm), eb = __expf(b-nm);
      d = d*sc + eb;
      c0 = c0*sc + eb*bflo(uv.x); c1 = c1*sc + eb*bfhi(uv.x);
      c2 = c2*sc + eb*bflo(uv.y); c3 = c3*sc + eb*bfhi(uv.y);
      m = nm;
    }
    float inv2 = 1.f/d;
    a0=c0*inv2; a1=c1*inv2; a2=c2*inv2; a3=c3*inv2;
  }

  if(half==0){
    const v4f* A4 = (const v4f*)bnA_l;
    const v4f* S4 = (const v4f*)bnS_l;
    v4f A = A4[l], S = S4[l];
    uint2 hr = ((const uint2*)h16)[(size_t)node*32 + l];
    float o0 = fmaxf(a0*A.x+S.x, 0.f) + bflo(hr.x);
    float o1 = fmaxf(a1*A.y+S.y, 0.f) + bfhi(hr.x);
    float o2 = fmaxf(a2*A.z+S.z, 0.f) + bflo(hr.y);
    float o3 = fmaxf(a3*A.w+S.w, 0.f) + bfhi(hr.y);
    uint2 p;
    p.x = (unsigned)f2bf_bits(o0) | ((unsigned)f2bf_bits(o1)<<16);
    p.y = (unsigned)f2bf_bits(o2) | ((unsigned)f2bf_bits(o3)<<16);
    ((uint2*)h16)[(size_t)node*32 + l] = p;
  }
}

// fused pool + head
__global__ void k_tail(const unsigned* __restrict__ h16, const int* __restrict__ batch,
   const float* __restrict__ gf,
   const float* __restrict__ gc_w, const float* __restrict__ gc_b,
   const float* __restrict__ gf1_w, const float* __restrict__ gf1_b,
   const float* __restrict__ gf2_w, const float* __restrict__ gf2_b,
   const float* __restrict__ p1_w, const float* __restrict__ p1_b,
   const float* __restrict__ p2_w, const float* __restrict__ p2_b,
   const float* __restrict__ p3_w, const float* __restrict__ p3_b,
   float* __restrict__ out){
  __shared__ float sg[384];
  __shared__ int sb[2];
  __shared__ float comb[192];
  __shared__ float hid1[64];
  __shared__ float r1[128];
  __shared__ float r2[64];
  int g = blockIdx.x, t = threadIdx.x;
  if(t < 2){
    int target = g + t;
    int lo=0, hi=N_NODES;
    while(lo<hi){ int mid=(lo+hi)>>1; if(batch[mid] < target) lo=mid+1; else hi=mid; }
    sb[t]=lo;
  }
  __syncthreads();
  {
    int s = sb[0], e = sb[1];
    int u = ((t>>5)<<4) + (t&15);
    int hiflag = (t>>4)&1;
    float sum=0.f, mx=-3.4e38f;
    for(int i=s;i<e;++i){
      unsigned uv = h16[(size_t)i*64 + u];
      float v = hiflag ? bfhi(uv) : bflo(uv);
      sum+=v; mx=fmaxf(mx,v);
    }
    int cnt = e-s;
    float meanv = sum / (float)(cnt>1?cnt:1);
    if(cnt==0) mx=0.f;
    sg[t] = meanv;
    sg[128+t] = mx;
    sg[256+t] = sum;
  }
  if(t<64){
    float a = gf1_b[t];
    #pragma unroll
    for(int i=0;i<10;++i) a += gf[g*10+i]*gf1_w[i*64+t];
    hid1[t] = fmaxf(a,0.f);
  }
  __syncthreads();
  if(t<64){
    float a = gf2_b[t];
    for(int k=0;k<64;++k) a += hid1[k]*gf2_w[k*64+t];
    comb[128+t] = a;
  }
  {
    float a = gc_b[t];
    for(int k=0;k<384;++k) a += sg[k]*gc_w[k*128+t];
    comb[t] = fmaxf(a,0.f);
  }
  __syncthreads();
  {
    float a = p1_b[t];
    for(int k=0;k<192;++k) a += comb[k]*p1_w[k*128+t];
    r1[t] = fmaxf(a,0.f);
  }
  __syncthreads();
  if(t<64){
    float a = p2_b[t];
    for(int k=0;k<128;++k) a += r1[k]*p2_w[k*64+t];
    r2[t] = fmaxf(a,0.f);
  }
  __syncthreads();
  if(t<TOUT){
    float a = p3_b[t];
    for(int k=0;k<64;++k) a += r2[k]*p3_w[k*TOUT+t];
    out[g*TOUT+t] = a;
  }
}

extern "C" void kernel_launch(void* const* d_in, const int* in_sizes, int n_in,
                              void* d_out, int out_size, void* d_ws, size_t ws_size,
                              hipStream_t stream){
  (void)in_sizes; (void)n_in; (void)out_size; (void)ws_size;
  const float* x        = (const float*)d_in[0];
  const int*   ei       = (const int*)d_in[1];
  const float* ea       = (const float*)d_in[2];
  const int*   batch    = (const int*)d_in[3];
  const float* gfin     = (const float*)d_in[4];
  const float* node_w   = (const float*)d_in[5];
  const float* node_b   = (const float*)d_in[6];
  const float* edge_w   = (const float*)d_in[7];
  const float* edge_b   = (const float*)d_in[8];
  const float* gat_lin_w  = (const float*)d_in[9];
  const float* gat_edge_w = (const float*)d_in[10];
  const float* att_src  = (const float*)d_in[11];
  const float* att_dst  = (const float*)d_in[12];
  const float* att_edge = (const float*)d_in[13];
  const float* gat_bias = (const float*)d_in[14];
  const float* bn_gamma = (const float*)d_in[15];
  const float* bn_beta  = (const float*)d_in[16];
  const float* bn_mean  = (const float*)d_in[17];
  const float* bn_var   = (const float*)d_in[18];
  const float* gc_w = (const float*)d_in[19];
  const float* gc_b = (const float*)d_in[20];
  const float* gf1_w = (const float*)d_in[21];
  const float* gf1_b = (const float*)d_in[22];
  const float* gf2_w = (const float*)d_in[23];
  const float* gf2_b = (const float*)d_in[24];
  const float* p1_w = (const float*)d_in[25];
  const float* p1_b = (const float*)d_in[26];
  const float* p2_w = (const float*)d_in[27];
  const float* p2_b = (const float*)d_in[28];
  const float* p3_w = (const float*)d_in[29];
  const float* p3_b = (const float*)d_in[30];
  float* out = (float*)d_out;

  char* w = (char*)d_ws;
  size_t o = 0;
  auto carve = [&](size_t bytes)->char*{
    char* p = w + o; o += (bytes + 255) & ~(size_t)255; return p;
  };
  unsigned* xhb = (unsigned*)carve((size_t)N_NODES*64*4);
  unsigned* h16 = (unsigned*)carve((size_t)N_NODES*64*4);
  float* ea_csr = (float*)carve((size_t)N_EDGES*4*4);
  float* as_    = (float*)carve((size_t)N_NODES*4*4);
  float* ad_    = (float*)carve((size_t)N_NODES*4*4);
  int* deg      = (int*)carve((size_t)N_NODES*4);
  int* rowptr   = (int*)carve((size_t)(N_NODES+1)*4);
  int* fill     = (int*)carve((size_t)N_NODES*4);
  int* csr_src  = (int*)carve((size_t)N_EDGES*4);
  int* part     = (int*)carve(1024*4);
  float* mebuf  = (float*)carve(64*4);
  float* bnA    = (float*)carve((size_t)NLAYER*HID*4);
  float* bnS    = (float*)carve((size_t)NLAYER*HID*4);
  unsigned short* whi = (unsigned short*)carve(65536*2);
  unsigned short* wlo = (unsigned short*)carve(65536*2);
  unsigned short* whiE = (unsigned short*)carve(8192*2);
  unsigned short* wloE = (unsigned short*)carve(8192*2);

  // setup: prep + w_ext + wswz + zero(deg,fill)   [replaces 2 memsets]
  int zb = (N_NODES+255)/256;
  k_setup<<<1 + 1024 + 256 + zb, 256, 0, stream>>>(gat_edge_w, att_edge, edge_w, edge_b,
        gat_bias, bn_gamma, bn_beta, bn_mean, bn_var,
        gat_lin_w, att_src, att_dst, mebuf, bnA, bnS, whiE, wloE, whi, wlo, deg, fill);
  k_init<<<N_NODES/4 + (N_EDGES+255)/256, 256, 0, stream>>>(x, node_w, node_b, h16, ei, deg);
  int nb = (N_NODES+1023)/1024;
  k_scan1<<<nb,256,0,stream>>>(deg, part);
  k_scan2<<<1,64,0,stream>>>(part, rowptr, nb);
  k_scan3<<<nb,256,0,stream>>>(deg, part, rowptr);
  k_fill<<<(N_EDGES+255)/256,256,0,stream>>>(ei, ea, rowptr, fill, csr_src, ea_csr);

  for(int l=0;l<NLAYER;++l){
    k_gemm<<<(N_NODES+63)/64,256,0,stream>>>((const unsigned short*)h16,
        whi + l*16384, wlo + l*16384, whiE + l*2048, wloE + l*2048,
        xhb, as_, ad_);
    k_aggr<<<(N_NODES+3)/4,256,0,stream>>>(xhb, as_, ad_, ea_csr, mebuf,
        rowptr, csr_src, bnA + l*128, bnS + l*128, h16, l);
  }

  k_tail<<<N_GRAPHS,128,0,stream>>>(h16, batch, gfin, gc_w, gc_b, gf1_w, gf1_b,
        gf2_w, gf2_b, p1_w, p1_b, p2_w, p2_b, p3_w, p3_b, out);
}

// Round 16
// 525.390 us; speedup vs baseline: 1.8565x; 1.0571x over previous
//
#include <hip/hip_runtime.h>

#define N_NODES 100000
#define N_EDGES 400000
#define N_GRAPHS 2048
#define HID 128
#define NLAYER 4
#define TOUT 5
#define EPSV 1e-5f
#define SLOPE 0.2f
#define MAXDEG 32
#define NB 98   // (N_NODES+1023)/1024

typedef float v4f __attribute__((ext_vector_type(4)));
typedef __bf16 v8bf __attribute__((ext_vector_type(8)));

static __device__ __forceinline__ unsigned short f2bf_bits(float f){
  unsigned u = __builtin_bit_cast(unsigned, f);
  unsigned r = u + 0x7fffu + ((u >> 16) & 1u);
  return (unsigned short)(r >> 16);
}
static __device__ __forceinline__ float bfbits2f(unsigned short s){
  unsigned u = ((unsigned)s) << 16;
  return __builtin_bit_cast(float, u);
}
static __device__ __forceinline__ float bflo(unsigned u){
  return __builtin_bit_cast(float, u << 16);
}
static __device__ __forceinline__ float bfhi(unsigned u){
  return __builtin_bit_cast(float, u & 0xffff0000u);
}
static __device__ __forceinline__ float lrelu(float v){
  return v>0.f ? v : SLOPE*v;
}

// Physical bf16 layout (head-aligned pairing):
//   word u (0..63): b=u>>4, r=u&15 -> holds channels (b*32+r [lo], b*32+16+r [hi]).
//   Lane l (words 2l,2l+1) is entirely head l>>3.
//   contraction position for channel k: kp = (k>>5)*32 + (k&15)*2 + ((k>>4)&1).

// merged setup: block 0 = prep; 1..1024 = w_ext (split hi/lo); 1025..1280 = wswz
// (single bf16 W); 1281.. = zero deg/fill
__global__ void k_setup(const float* __restrict__ gat_edge_w, const float* __restrict__ att_edge,
                        const float* __restrict__ edge_w, const float* __restrict__ edge_b,
                        const float* __restrict__ gat_bias, const float* __restrict__ gamma,
                        const float* __restrict__ beta, const float* __restrict__ mean,
                        const float* __restrict__ var, const float* __restrict__ gat_lin_w,
                        const float* __restrict__ att_src, const float* __restrict__ att_dst,
                        float* __restrict__ mebuf, float* __restrict__ bnA, float* __restrict__ bnS,
                        unsigned short* __restrict__ whiE, unsigned short* __restrict__ wloE,
                        unsigned short* __restrict__ whi,
                        int* __restrict__ deg, int* __restrict__ fill){
  __shared__ float Ve[128*16];
  int bid = blockIdx.x, t = threadIdx.x;
  if(bid == 0){
    for(int i=t; i<NLAYER*HID; i+=256){
      int l_ = i>>7, pos = i&127, lane = pos>>2, j = pos&3;
      int ch = ((lane>>3)<<5) + ((lane&7)<<1) + ((j&1)<<4) + (j>>1);
      int src = l_*128 + ch;
      float A = gamma[src]*rsqrtf(var[src]+EPSV);
      bnA[i] = A;
      bnS[i] = (gat_bias[src]-mean[src])*A + beta[src];
    }
    for(int id=t; id<2048; id+=256){
      int k = id>>4, li = id&15, l = li>>2, hh = li&3;
      const float* gw = gat_edge_w + l*16384 + k*128 + hh*32;
      const float* at = att_edge + l*128 + hh*32;
      float s = 0.f;
      #pragma unroll
      for(int c=0;c<32;++c) s += gw[c]*at[c];
      Ve[k*16+li] = s;
    }
    __syncthreads();
    if(t < 48){
      int f = t>>4, li = t&15;
      float s=0.f;
      for(int k=0;k<128;++k) s += edge_w[f*128+k]*Ve[k*16+li];
      mebuf[f*16+li] = s;
    } else if (t < 64){
      int li = t-48; float s=0.f;
      for(int k=0;k<128;++k) s += edge_b[k]*Ve[k*16+li];
      mebuf[48+li] = s;
    }
  } else if(bid <= 1024){
    int wave = t>>6, lane = t&63;
    int i = (bid-1)*8 + wave*2 + (lane>>5);   // 0..8191
    int l_ = i>>11, rest = i&2047, kp = rest>>4, col = rest&15;
    int sub = lane&31;
    float val = 0.f;
    if(col < 8){
      int h_ = col&3, isdst = col>>2;
      int ch = ((kp>>5)<<5) + ((kp&1)<<4) + ((kp&31)>>1);
      const float* at = (isdst? att_dst : att_src);
      val = gat_lin_w[l_*16384 + ch*128 + h_*32 + sub] * at[l_*128 + h_*32 + sub];
    }
    val += __shfl_xor(val,1); val += __shfl_xor(val,2); val += __shfl_xor(val,4);
    val += __shfl_xor(val,8); val += __shfl_xor(val,16);
    if(sub == 0){
      unsigned short hi = f2bf_bits(val);
      unsigned short lo = f2bf_bits(val - bfbits2f(hi));
      int kb=kp>>5, quad=(kp>>3)&3, jj=kp&7, lane2=quad*16+col;
      int dst = ((l_*4+kb)*64 + lane2)*8 + jj;
      whiE[dst]=hi; wloE[dst]=lo;
    }
  } else if(bid <= 1280){
    int tg = (bid-1025)*256 + t;              // 0..65535 == dst index
    int base = tg>>9, off = tg&511;
    int l = base>>5, kb=(base>>3)&3, cg=base&7;
    int lane = off>>3, j = off&7;
    int quad = lane>>4, r = lane&15;
    int kp = kb*32 + quad*8 + j;
    int k = ((kp>>5)<<5) | ((kp&1)<<4) | ((kp&31)>>1);
    whi[tg] = f2bf_bits(gat_lin_w[l*16384 + k*128 + cg*16 + r]);
  } else {
    int tg = (bid-1281)*256 + t;
    if(tg < N_NODES){ deg[tg]=0; fill[tg]=0; }
  }
}

// merged init: blocks 0..24999 = hinit; 25000.. = deg
__global__ void k_init(const float* __restrict__ x, const float* __restrict__ nw,
                       const float* __restrict__ nb, unsigned* __restrict__ h16,
                       const int* __restrict__ ei, int* __restrict__ deg){
  int bid = blockIdx.x, t = threadIdx.x;
  if(bid < N_NODES/4){
    int node = bid*4 + (t>>6);
    int c = t&63;
    int ch = ((c>>4)<<5) + (c&15);
    float a0 = nb[ch], a1 = nb[ch+16];
    #pragma unroll
    for(int f=0; f<7; ++f){
      float xv = x[node*7+f];
      a0 += xv*nw[f*HID+ch];
      a1 += xv*nw[f*HID+ch+16];
    }
    unsigned p = (unsigned)f2bf_bits(a0) | ((unsigned)f2bf_bits(a1)<<16);
    h16[(size_t)node*64 + c] = p;
  } else {
    int e = (bid - N_NODES/4)*256 + t;
    if(e < N_EDGES) atomicAdd(&deg[ei[N_EDGES+e]], 1);
  }
}

// scan phase 1: per-chunk sums
__global__ void k_scan1(const int* __restrict__ deg, int* __restrict__ part){
  __shared__ int s[256];
  int t=threadIdx.x; int base = blockIdx.x*1024 + t*4;
  int sum=0;
  #pragma unroll
  for(int j=0;j<4;++j){ int i=base+j; sum += (i<N_NODES)? deg[i]:0; }
  s[t]=sum; __syncthreads();
  for(int off=128; off>0; off>>=1){ if(t<off) s[t]+=s[t+off]; __syncthreads(); }
  if(t==0) part[blockIdx.x]=s[0];
}
// scan phase 2+3 fused: each block serially prefixes the 98 partials (scalar),
// then scans its own chunk -> rowptr
__global__ void k_scan3(const int* __restrict__ deg, const int* __restrict__ part,
                        int* __restrict__ rowptr){
  __shared__ int s[256];
  int t=threadIdx.x, b=blockIdx.x;
  int g = 0, tot = 0;
  for(int i=0;i<NB;++i){ int v = part[i]; g += (i<b)? v : 0; tot += v; }
  if(b==0 && t==0) rowptr[N_NODES]=tot;
  int base = b*1024 + t*4;
  int v[4]; int sum=0; int pre[4];
  #pragma unroll
  for(int j=0;j<4;++j){ int i=base+j; v[j]=(i<N_NODES)?deg[i]:0; pre[j]=sum; sum+=v[j]; }
  s[t]=sum; __syncthreads();
  for(int off=1; off<256; off<<=1){
    int xv = (t>=off)? s[t-off]:0; __syncthreads();
    s[t]+=xv; __syncthreads();
  }
  int toff = (t>0)? s[t-1]:0;
  #pragma unroll
  for(int j=0;j<4;++j){ int i=base+j; if(i<N_NODES) rowptr[i]=g+toff+pre[j]; }
}

// build CSR: src ids + edge_attr (padded to float4)
__global__ void k_fill(const int* __restrict__ ei, const float* __restrict__ ea,
                       const int* __restrict__ rowptr, int* __restrict__ fill,
                       int* __restrict__ csr_src, float* __restrict__ ea_csr){
  int e = blockIdx.x*256+threadIdx.x;
  if(e>=N_EDGES) return;
  int dst = ei[N_EDGES+e];
  int pos = rowptr[dst] + atomicAdd(&fill[dst],1);
  csr_src[pos] = ei[e];
  v4f q = {ea[e*3], ea[e*3+1], ea[e*3+2], 0.f};
  ((v4f*)ea_csr)[pos] = q;
}

// xh = h16 @ W[l] (both bf16, single MFMA per fragment); as_/ad_ via split-precision
// w_ext MFMA tile. xhb pack staged through LDS -> coalesced 256B row stores.
__global__ void k_gemm(const unsigned short* __restrict__ h16,
                       const unsigned short* __restrict__ whi,
                       const unsigned short* __restrict__ whiE,
                       const unsigned short* __restrict__ wloE,
                       unsigned* __restrict__ xhb, float* __restrict__ as_, float* __restrict__ ad_){
  __shared__ unsigned sxh[4][16*68];
  int wave = threadIdx.x>>6, lane = threadIdx.x&63;
  int row0 = blockIdx.x*64 + wave*16;
  if(row0 > N_NODES-16) row0 = N_NODES-16;   // clamp: duplicate work, identical values
  int q = lane>>4, r = lane&15;
  const unsigned short* hrow = h16 + (size_t)(row0 + r)*HID;
  v8bf av[4];
  #pragma unroll
  for(int kb=0;kb<4;++kb)
    av[kb] = *(const v8bf*)(hrow + kb*32 + q*8);
  v4f acc[8];
  #pragma unroll
  for(int cg=0;cg<8;++cg){
    v4f a = {0.f,0.f,0.f,0.f};
    #pragma unroll
    for(int kb=0;kb<4;++kb){
      v8bf bhi = *(const v8bf*)(whi + ((kb*8+cg)*64 + lane)*8);
      a = __builtin_amdgcn_mfma_f32_16x16x32_bf16(av[kb], bhi, a, 0,0,0);
    }
    acc[cg]=a;
  }
  v4f acc8 = {0.f,0.f,0.f,0.f};
  #pragma unroll
  for(int kb=0;kb<4;++kb){
    v8bf bhi = *(const v8bf*)(whiE + (kb*64 + lane)*8);
    v8bf blo = *(const v8bf*)(wloE + (kb*64 + lane)*8);
    acc8 = __builtin_amdgcn_mfma_f32_16x16x32_bf16(av[kb], blo, acc8, 0,0,0);
    acc8 = __builtin_amdgcn_mfma_f32_16x16x32_bf16(av[kb], bhi, acc8, 0,0,0);
  }
  // stage packed words in LDS (stride 68 words -> 2-way banking, free)
  #pragma unroll
  for(int m=0;m<4;++m){
    #pragma unroll
    for(int reg=0;reg<4;++reg){
      unsigned pack = (unsigned)f2bf_bits(acc[2*m][reg]) | ((unsigned)f2bf_bits(acc[2*m+1][reg])<<16);
      sxh[wave][(q*4+reg)*68 + m*16 + r] = pack;
    }
  }
  __syncthreads();
  // coalesced write-back: one full 256B row per instruction
  {
    int rr = lane>>4, c4 = lane&15;
    #pragma unroll
    for(int rg=0; rg<4; ++rg){
      int i = rg*4 + rr;
      uint4 v = *(const uint4*)&sxh[wave][i*68 + c4*4];
      *(uint4*)(xhb + (size_t)(row0 + i)*64 + c4*4) = v;
    }
  }
  if(r < 4){
    #pragma unroll
    for(int reg=0;reg<4;++reg)
      as_[(size_t)(row0 + q*4 + reg)*4 + r] = acc8[reg];
  } else if(r < 8){
    #pragma unroll
    for(int reg=0;reg<4;++reg)
      ad_[(size_t)(row0 + q*4 + reg)*4 + (r-4)] = acc8[reg];
  }
}

// wave-per-node. Phase A: parallel softmax anchored at self-logit; deg<=16 fast
// path. Phase B: half-wave uint2 gather (lane's 4 channels all in head l>>3).
// Epilogue: permuted folded BN + relu + bf16 residual; writes h16.
__global__ void k_aggr(const unsigned* __restrict__ xhb, const float* __restrict__ as_,
    const float* __restrict__ ad_, const float* __restrict__ ea_csr,
    const float* __restrict__ mebuf,
    const int* __restrict__ rowptr, const int* __restrict__ csr_src,
    const float* __restrict__ bnA_l, const float* __restrict__ bnS_l,
    unsigned* __restrict__ h16, int layer){
  __shared__ float lds_coef[4][MAXDEG*4];
  __shared__ int   lds_src[4][MAXDEG];
  int w = threadIdx.x>>6, lane = threadIdx.x&63;
  int node = blockIdx.x*4 + w;
  if(node >= N_NODES) return;
  int s = rowptr[node], e = rowptr[node+1];
  int deg = e - s;
  int l = lane&31, half = lane>>5, hh2 = l>>3;
  const uint2* xrow = (const uint2*)xhb;
  float a0,a1,a2,a3;

  if(deg <= MAXDEG){
    int eidx = lane>>2, h = lane&3;
    int li = layer*4+h;
    float mec0=mebuf[li], mec1=mebuf[16+li], mec2=mebuf[32+li], meb=mebuf[48+li];
    float ad_h = ad_[node*4+h];
    int j0 = eidx;
    float t0 = 0.f, g0 = 0.f;
    int s0 = node;
    bool v0 = (j0 < deg);
    if(v0){
      s0 = csr_src[s+j0];
      v4f qq = ((const v4f*)ea_csr)[s+j0];
      t0 = qq.x*mec0 + qq.y*mec1 + qq.z*mec2;
      g0 = lrelu(as_[s0*4+h] + ad_h + t0 + meb);
    }
    float ts, ds, inv;
    if(deg <= 16){
      ts = t0;
      ts += __shfl_xor(ts,4); ts += __shfl_xor(ts,8);
      ts += __shfl_xor(ts,16); ts += __shfl_xor(ts,32);
      float lt = (deg>0) ? ts/(float)deg + meb : 0.f;
      float al = lrelu(as_[node*4+h] + ad_h + lt);
      float e0 = v0 ? __expf(g0-al) : 0.f;
      ds = e0;
      ds += __shfl_xor(ds,4); ds += __shfl_xor(ds,8);
      ds += __shfl_xor(ds,16); ds += __shfl_xor(ds,32);
      inv = 1.f/(ds+1.f);
      lds_src[w][j0] = s0;
      lds_coef[w][j0*4+h] = e0*inv;
    } else {
      int j1 = 16+eidx;
      float t1 = 0.f, g1 = 0.f;
      int s1 = node;
      bool v1 = (j1 < deg);
      if(v1){
        s1 = csr_src[s+j1];
        v4f qq = ((const v4f*)ea_csr)[s+j1];
        t1 = qq.x*mec0 + qq.y*mec1 + qq.z*mec2;
        g1 = lrelu(as_[s1*4+h] + ad_h + t1 + meb);
      }
      ts = t0+t1;
      ts += __shfl_xor(ts,4); ts += __shfl_xor(ts,8);
      ts += __shfl_xor(ts,16); ts += __shfl_xor(ts,32);
      float lt = ts/(float)deg + meb;
      float al = lrelu(as_[node*4+h] + ad_h + lt);
      float e0 = v0 ? __expf(g0-al) : 0.f;
      float e1 = v1 ? __expf(g1-al) : 0.f;
      ds = e0+e1;
      ds += __shfl_xor(ds,4); ds += __shfl_xor(ds,8);
      ds += __shfl_xor(ds,16); ds += __shfl_xor(ds,32);
      inv = 1.f/(ds+1.f);
      if(h==0){ lds_src[w][j0]=s0; lds_src[w][j1]=s1; }
      lds_coef[w][j0*4+h] = e0*inv;
      lds_coef[w][j1*4+h] = e1*inv;
    }
    // ---- phase B ----
    float cs4 = __shfl(inv, hh2);
    uint2 su = xrow[(size_t)node*32 + l];
    int pdeg = (deg+3)&~3;
    a0=a1=a2=a3=0.f;
    for(int j=0;j<pdeg;j+=4){
      float ca = lds_coef[w][(j+half)*4+hh2];
      float cb = lds_coef[w][(j+2+half)*4+hh2];
      int sa = lds_src[w][j+half], sb = lds_src[w][j+2+half];
      uint2 ua = xrow[(size_t)sa*32+l];
      uint2 ub = xrow[(size_t)sb*32+l];
      a0 += ca*bflo(ua.x) + cb*bflo(ub.x);
      a1 += ca*bfhi(ua.x) + cb*bfhi(ub.x);
      a2 += ca*bflo(ua.y) + cb*bflo(ub.y);
      a3 += ca*bfhi(ua.y) + cb*bfhi(ub.y);
    }
    a0 += __shfl_xor(a0,32); a1 += __shfl_xor(a1,32);
    a2 += __shfl_xor(a2,32); a3 += __shfl_xor(a3,32);
    a0 += cs4*bflo(su.x); a1 += cs4*bfhi(su.x);
    a2 += cs4*bflo(su.y); a3 += cs4*bfhi(su.y);
  } else {
    int li = layer*4+hh2;
    float mec0=mebuf[li], mec1=mebuf[16+li], mec2=mebuf[32+li], meb=mebuf[48+li];
    float adv = ad_[node*4+hh2];
    float ts = 0.f;
    for(int j=s;j<e;++j){
      v4f qq = ((const v4f*)ea_csr)[j];
      ts += qq.x*mec0 + qq.y*mec1 + qq.z*mec2;
    }
    float al = lrelu(as_[node*4+hh2] + adv + ts/(float)deg + meb);
    float m = al, d = 1.f;
    uint2 su = xrow[(size_t)node*32 + l];
    float c0=bflo(su.x),c1=bfhi(su.x),c2=bflo(su.y),c3=bfhi(su.y);
    for(int j=s;j<e;++j){
      int sr = csr_src[j];
      v4f qq = ((const v4f*)ea_csr)[j];
      float b = lrelu(as_[sr*4+hh2] + adv + qq.x*mec0+qq.y*mec1+qq.z*mec2+meb);
      uint2 uv = xrow[(size_t)sr*32 + l];
      float nm = fmaxf(m,b);
      float sc = __expf(m-nm), eb = __expf(b-nm);
      d = d*sc + eb;
      c0 = c0*sc + eb*bflo(uv.x); c1 = c1*sc + eb*bfhi(uv.x);
      c2 = c2*sc + eb*bflo(uv.y); c3 = c3*sc + eb*bfhi(uv.y);
      m = nm;
    }
    float inv2 = 1.f/d;
    a0=c0*inv2; a1=c1*inv2; a2=c2*inv2; a3=c3*inv2;
  }

  if(half==0){
    const v4f* A4 = (const v4f*)bnA_l;
    const v4f* S4 = (const v4f*)bnS_l;
    v4f A = A4[l], S = S4[l];
    uint2 hr = ((const uint2*)h16)[(size_t)node*32 + l];
    float o0 = fmaxf(a0*A.x+S.x, 0.f) + bflo(hr.x);
    float o1 = fmaxf(a1*A.y+S.y, 0.f) + bfhi(hr.x);
    float o2 = fmaxf(a2*A.z+S.z, 0.f) + bflo(hr.y);
    float o3 = fmaxf(a3*A.w+S.w, 0.f) + bfhi(hr.y);
    uint2 p;
    p.x = (unsigned)f2bf_bits(o0) | ((unsigned)f2bf_bits(o1)<<16);
    p.y = (unsigned)f2bf_bits(o2) | ((unsigned)f2bf_bits(o3)<<16);
    ((uint2*)h16)[(size_t)node*32 + l] = p;
  }
}

// fused pool + head
__global__ void k_tail(const unsigned* __restrict__ h16, const int* __restrict__ batch,
   const float* __restrict__ gf,
   const float* __restrict__ gc_w, const float* __restrict__ gc_b,
   const float* __restrict__ gf1_w, const float* __restrict__ gf1_b,
   const float* __restrict__ gf2_w, const float* __restrict__ gf2_b,
   const float* __restrict__ p1_w, const float* __restrict__ p1_b,
   const float* __restrict__ p2_w, const float* __restrict__ p2_b,
   const float* __restrict__ p3_w, const float* __restrict__ p3_b,
   float* __restrict__ out){
  __shared__ float sg[384];
  __shared__ int sb[2];
  __shared__ float comb[192];
  __shared__ float hid1[64];
  __shared__ float r1[128];
  __shared__ float r2[64];
  int g = blockIdx.x, t = threadIdx.x;
  if(t < 2){
    int target = g + t;
    int lo=0, hi=N_NODES;
    while(lo<hi){ int mid=(lo+hi)>>1; if(batch[mid] < target) lo=mid+1; else hi=mid; }
    sb[t]=lo;
  }
  __syncthreads();
  {
    int s = sb[0], e = sb[1];
    int u = ((t>>5)<<4) + (t&15);
    int hiflag = (t>>4)&1;
    float sum=0.f, mx=-3.4e38f;
    for(int i=s;i<e;++i){
      unsigned uv = h16[(size_t)i*64 + u];
      float v = hiflag ? bfhi(uv) : bflo(uv);
      sum+=v; mx=fmaxf(mx,v);
    }
    int cnt = e-s;
    float meanv = sum / (float)(cnt>1?cnt:1);
    if(cnt==0) mx=0.f;
    sg[t] = meanv;
    sg[128+t] = mx;
    sg[256+t] = sum;
  }
  if(t<64){
    float a = gf1_b[t];
    #pragma unroll
    for(int i=0;i<10;++i) a += gf[g*10+i]*gf1_w[i*64+t];
    hid1[t] = fmaxf(a,0.f);
  }
  __syncthreads();
  if(t<64){
    float a = gf2_b[t];
    for(int k=0;k<64;++k) a += hid1[k]*gf2_w[k*64+t];
    comb[128+t] = a;
  }
  {
    float a = gc_b[t];
    for(int k=0;k<384;++k) a += sg[k]*gc_w[k*128+t];
    comb[t] = fmaxf(a,0.f);
  }
  __syncthreads();
  {
    float a = p1_b[t];
    for(int k=0;k<192;++k) a += comb[k]*p1_w[k*128+t];
    r1[t] = fmaxf(a,0.f);
  }
  __syncthreads();
  if(t<64){
    float a = p2_b[t];
    for(int k=0;k<128;++k) a += r1[k]*p2_w[k*64+t];
    r2[t] = fmaxf(a,0.f);
  }
  __syncthreads();
  if(t<TOUT){
    float a = p3_b[t];
    for(int k=0;k<64;++k) a += r2[k]*p3_w[k*TOUT+t];
    out[g*TOUT+t] = a;
  }
}

extern "C" void kernel_launch(void* const* d_in, const int* in_sizes, int n_in,
                              void* d_out, int out_size, void* d_ws, size_t ws_size,
                              hipStream_t stream){
  (void)in_sizes; (void)n_in; (void)out_size; (void)ws_size;
  const float* x        = (const float*)d_in[0];
  const int*   ei       = (const int*)d_in[1];
  const float* ea       = (const float*)d_in[2];
  const int*   batch    = (const int*)d_in[3];
  const float* gfin     = (const float*)d_in[4];
  const float* node_w   = (const float*)d_in[5];
  const float* node_b   = (const float*)d_in[6];
  const float* edge_w   = (const float*)d_in[7];
  const float* edge_b   = (const float*)d_in[8];
  const float* gat_lin_w  = (const float*)d_in[9];
  const float* gat_edge_w = (const float*)d_in[10];
  const float* att_src  = (const float*)d_in[11];
  const float* att_dst  = (const float*)d_in[12];
  const float* att_edge = (const float*)d_in[13];
  const float* gat_bias = (const float*)d_in[14];
  const float* bn_gamma = (const float*)d_in[15];
  const float* bn_beta  = (const float*)d_in[16];
  const float* bn_mean  = (const float*)d_in[17];
  const float* bn_var   = (const float*)d_in[18];
  const float* gc_w = (const float*)d_in[19];
  const float* gc_b = (const float*)d_in[20];
  const float* gf1_w = (const float*)d_in[21];
  const float* gf1_b = (const float*)d_in[22];
  const float* gf2_w = (const float*)d_in[23];
  const float* gf2_b = (const float*)d_in[24];
  const float* p1_w = (const float*)d_in[25];
  const float* p1_b = (const float*)d_in[26];
  const float* p2_w = (const float*)d_in[27];
  const float* p2_b = (const float*)d_in[28];
  const float* p3_w = (const float*)d_in[29];
  const float* p3_b = (const float*)d_in[30];
  float* out = (float*)d_out;

  char* w = (char*)d_ws;
  size_t o = 0;
  auto carve = [&](size_t bytes)->char*{
    char* p = w + o; o += (bytes + 255) & ~(size_t)255; return p;
  };
  unsigned* xhb = (unsigned*)carve((size_t)N_NODES*64*4);
  unsigned* h16 = (unsigned*)carve((size_t)N_NODES*64*4);
  float* ea_csr = (float*)carve((size_t)N_EDGES*4*4);
  float* as_    = (float*)carve((size_t)N_NODES*4*4);
  float* ad_    = (float*)carve((size_t)N_NODES*4*4);
  int* deg      = (int*)carve((size_t)N_NODES*4);
  int* rowptr   = (int*)carve((size_t)(N_NODES+1)*4);
  int* fill     = (int*)carve((size_t)N_NODES*4);
  int* csr_src  = (int*)carve((size_t)N_EDGES*4);
  int* part     = (int*)carve(1024*4);
  float* mebuf  = (float*)carve(64*4);
  float* bnA    = (float*)carve((size_t)NLAYER*HID*4);
  float* bnS    = (float*)carve((size_t)NLAYER*HID*4);
  unsigned short* whi = (unsigned short*)carve(65536*2);
  unsigned short* whiE = (unsigned short*)carve(8192*2);
  unsigned short* wloE = (unsigned short*)carve(8192*2);

  // setup: prep + w_ext + wswz + zero(deg,fill)
  int zb = (N_NODES+255)/256;
  k_setup<<<1 + 1024 + 256 + zb, 256, 0, stream>>>(gat_edge_w, att_edge, edge_w, edge_b,
        gat_bias, bn_gamma, bn_beta, bn_mean, bn_var,
        gat_lin_w, att_src, att_dst, mebuf, bnA, bnS, whiE, wloE, whi, deg, fill);
  k_init<<<N_NODES/4 + (N_EDGES+255)/256, 256, 0, stream>>>(x, node_w, node_b, h16, ei, deg);
  k_scan1<<<NB,256,0,stream>>>(deg, part);
  k_scan3<<<NB,256,0,stream>>>(deg, part, rowptr);
  k_fill<<<(N_EDGES+255)/256,256,0,stream>>>(ei, ea, rowptr, fill, csr_src, ea_csr);

  for(int l=0;l<NLAYER;++l){
    k_gemm<<<(N_NODES+63)/64,256,0,stream>>>((const unsigned short*)h16,
        whi + l*16384, whiE + l*2048, wloE + l*2048,
        xhb, as_, ad_);
    k_aggr<<<(N_NODES+3)/4,256,0,stream>>>(xhb, as_, ad_, ea_csr, mebuf,
        rowptr, csr_src, bnA + l*128, bnS + l*128, h16, l);
  }

  k_tail<<<N_GRAPHS,128,0,stream>>>(h16, batch, gfin, gc_w, gc_b, gf1_w, gf1_b,
        gf2_w, gf2_b, p1_w, p1_b, p2_w, p2_b, p3_w, p3_b, out);
}

// Round 17
// 520.838 us; speedup vs baseline: 1.8727x; 1.0087x over previous
//
#include <hip/hip_runtime.h>

#define N_NODES 100000
#define N_EDGES 400000
#define N_GRAPHS 2048
#define HID 128
#define NLAYER 4
#define TOUT 5
#define EPSV 1e-5f
#define SLOPE 0.2f
#define MAXDEG 32
#define NB 98   // (N_NODES+1023)/1024

typedef float v4f __attribute__((ext_vector_type(4)));
typedef __bf16 v8bf __attribute__((ext_vector_type(8)));

static __device__ __forceinline__ unsigned short f2bf_bits(float f){
  unsigned u = __builtin_bit_cast(unsigned, f);
  unsigned r = u + 0x7fffu + ((u >> 16) & 1u);
  return (unsigned short)(r >> 16);
}
static __device__ __forceinline__ float bfbits2f(unsigned short s){
  unsigned u = ((unsigned)s) << 16;
  return __builtin_bit_cast(float, u);
}
static __device__ __forceinline__ float bflo(unsigned u){
  return __builtin_bit_cast(float, u << 16);
}
static __device__ __forceinline__ float bfhi(unsigned u){
  return __builtin_bit_cast(float, u & 0xffff0000u);
}
static __device__ __forceinline__ float lrelu(float v){
  return v>0.f ? v : SLOPE*v;
}

// Physical bf16 layout (head-aligned pairing):
//   word u (0..63): b=u>>4, r=u&15 -> holds channels (b*32+r [lo], b*32+16+r [hi]).
//   Lane l (words 2l,2l+1) is entirely head l>>3.
//   contraction position for channel k: kp = (k>>5)*32 + (k&15)*2 + ((k>>4)&1).

// merged setup: block 0 = prep; 1..1024 = w_ext (split hi/lo); 1025..1280 = wswz
// (single bf16 W); 1281.. = zero deg/fill
__global__ void k_setup(const float* __restrict__ gat_edge_w, const float* __restrict__ att_edge,
                        const float* __restrict__ edge_w, const float* __restrict__ edge_b,
                        const float* __restrict__ gat_bias, const float* __restrict__ gamma,
                        const float* __restrict__ beta, const float* __restrict__ mean,
                        const float* __restrict__ var, const float* __restrict__ gat_lin_w,
                        const float* __restrict__ att_src, const float* __restrict__ att_dst,
                        float* __restrict__ mebuf, float* __restrict__ bnA, float* __restrict__ bnS,
                        unsigned short* __restrict__ whiE, unsigned short* __restrict__ wloE,
                        unsigned short* __restrict__ whi,
                        int* __restrict__ deg, int* __restrict__ fill){
  __shared__ float Ve[128*16];
  int bid = blockIdx.x, t = threadIdx.x;
  if(bid == 0){
    for(int i=t; i<NLAYER*HID; i+=256){
      int l_ = i>>7, pos = i&127, lane = pos>>2, j = pos&3;
      int ch = ((lane>>3)<<5) + ((lane&7)<<1) + ((j&1)<<4) + (j>>1);
      int src = l_*128 + ch;
      float A = gamma[src]*rsqrtf(var[src]+EPSV);
      bnA[i] = A;
      bnS[i] = (gat_bias[src]-mean[src])*A + beta[src];
    }
    for(int id=t; id<2048; id+=256){
      int k = id>>4, li = id&15, l = li>>2, hh = li&3;
      const float* gw = gat_edge_w + l*16384 + k*128 + hh*32;
      const float* at = att_edge + l*128 + hh*32;
      float s = 0.f;
      #pragma unroll
      for(int c=0;c<32;++c) s += gw[c]*at[c];
      Ve[k*16+li] = s;
    }
    __syncthreads();
    if(t < 48){
      int f = t>>4, li = t&15;
      float s=0.f;
      for(int k=0;k<128;++k) s += edge_w[f*128+k]*Ve[k*16+li];
      mebuf[f*16+li] = s;
    } else if (t < 64){
      int li = t-48; float s=0.f;
      for(int k=0;k<128;++k) s += edge_b[k]*Ve[k*16+li];
      mebuf[48+li] = s;
    }
  } else if(bid <= 1024){
    int wave = t>>6, lane = t&63;
    int i = (bid-1)*8 + wave*2 + (lane>>5);   // 0..8191
    int l_ = i>>11, rest = i&2047, kp = rest>>4, col = rest&15;
    int sub = lane&31;
    float val = 0.f;
    if(col < 8){
      int h_ = col&3, isdst = col>>2;
      int ch = ((kp>>5)<<5) + ((kp&1)<<4) + ((kp&31)>>1);
      const float* at = (isdst? att_dst : att_src);
      val = gat_lin_w[l_*16384 + ch*128 + h_*32 + sub] * at[l_*128 + h_*32 + sub];
    }
    val += __shfl_xor(val,1); val += __shfl_xor(val,2); val += __shfl_xor(val,4);
    val += __shfl_xor(val,8); val += __shfl_xor(val,16);
    if(sub == 0){
      unsigned short hi = f2bf_bits(val);
      unsigned short lo = f2bf_bits(val - bfbits2f(hi));
      int kb=kp>>5, quad=(kp>>3)&3, jj=kp&7, lane2=quad*16+col;
      int dst = ((l_*4+kb)*64 + lane2)*8 + jj;
      whiE[dst]=hi; wloE[dst]=lo;
    }
  } else if(bid <= 1280){
    int tg = (bid-1025)*256 + t;              // 0..65535 == dst index
    int base = tg>>9, off = tg&511;
    int l = base>>5, kb=(base>>3)&3, cg=base&7;
    int lane = off>>3, j = off&7;
    int quad = lane>>4, r = lane&15;
    int kp = kb*32 + quad*8 + j;
    int k = ((kp>>5)<<5) | ((kp&1)<<4) | ((kp&31)>>1);
    whi[tg] = f2bf_bits(gat_lin_w[l*16384 + k*128 + cg*16 + r]);
  } else {
    int tg = (bid-1281)*256 + t;
    if(tg < N_NODES){ deg[tg]=0; fill[tg]=0; }
  }
}

// merged init: blocks 0..24999 = hinit; 25000.. = deg
__global__ void k_init(const float* __restrict__ x, const float* __restrict__ nw,
                       const float* __restrict__ nb, unsigned* __restrict__ h16,
                       const int* __restrict__ ei, int* __restrict__ deg){
  int bid = blockIdx.x, t = threadIdx.x;
  if(bid < N_NODES/4){
    int node = bid*4 + (t>>6);
    int c = t&63;
    int ch = ((c>>4)<<5) + (c&15);
    float a0 = nb[ch], a1 = nb[ch+16];
    #pragma unroll
    for(int f=0; f<7; ++f){
      float xv = x[node*7+f];
      a0 += xv*nw[f*HID+ch];
      a1 += xv*nw[f*HID+ch+16];
    }
    unsigned p = (unsigned)f2bf_bits(a0) | ((unsigned)f2bf_bits(a1)<<16);
    h16[(size_t)node*64 + c] = p;
  } else {
    int e = (bid - N_NODES/4)*256 + t;
    if(e < N_EDGES) atomicAdd(&deg[ei[N_EDGES+e]], 1);
  }
}

// scan phase 1: per-chunk sums
__global__ void k_scan1(const int* __restrict__ deg, int* __restrict__ part){
  __shared__ int s[256];
  int t=threadIdx.x; int base = blockIdx.x*1024 + t*4;
  int sum=0;
  #pragma unroll
  for(int j=0;j<4;++j){ int i=base+j; sum += (i<N_NODES)? deg[i]:0; }
  s[t]=sum; __syncthreads();
  for(int off=128; off>0; off>>=1){ if(t<off) s[t]+=s[t+off]; __syncthreads(); }
  if(t==0) part[blockIdx.x]=s[0];
}
// scan phase 2+3 fused: each block serially prefixes the 98 partials (scalar),
// then scans its own chunk -> rowptr
__global__ void k_scan3(const int* __restrict__ deg, const int* __restrict__ part,
                        int* __restrict__ rowptr){
  __shared__ int s[256];
  int t=threadIdx.x, b=blockIdx.x;
  int g = 0, tot = 0;
  for(int i=0;i<NB;++i){ int v = part[i]; g += (i<b)? v : 0; tot += v; }
  if(b==0 && t==0) rowptr[N_NODES]=tot;
  int base = b*1024 + t*4;
  int v[4]; int sum=0; int pre[4];
  #pragma unroll
  for(int j=0;j<4;++j){ int i=base+j; v[j]=(i<N_NODES)?deg[i]:0; pre[j]=sum; sum+=v[j]; }
  s[t]=sum; __syncthreads();
  for(int off=1; off<256; off<<=1){
    int xv = (t>=off)? s[t-off]:0; __syncthreads();
    s[t]+=xv; __syncthreads();
  }
  int toff = (t>0)? s[t-1]:0;
  #pragma unroll
  for(int j=0;j<4;++j){ int i=base+j; if(i<N_NODES) rowptr[i]=g+toff+pre[j]; }
}

// build CSR: src ids + edge_attr (padded to float4)
__global__ void k_fill(const int* __restrict__ ei, const float* __restrict__ ea,
                       const int* __restrict__ rowptr, int* __restrict__ fill,
                       int* __restrict__ csr_src, float* __restrict__ ea_csr){
  int e = blockIdx.x*256+threadIdx.x;
  if(e>=N_EDGES) return;
  int dst = ei[N_EDGES+e];
  int pos = rowptr[dst] + atomicAdd(&fill[dst],1);
  csr_src[pos] = ei[e];
  v4f q = {ea[e*3], ea[e*3+1], ea[e*3+2], 0.f};
  ((v4f*)ea_csr)[pos] = q;
}

// xh = h16 @ W[l], 2 row-tiles per wave (B-fragments reused -> half the weight
// traffic). as_/ad_ via split-precision w_ext tile. LDS-staged coalesced stores.
__global__ void k_gemm(const unsigned short* __restrict__ h16,
                       const unsigned short* __restrict__ whi,
                       const unsigned short* __restrict__ whiE,
                       const unsigned short* __restrict__ wloE,
                       unsigned* __restrict__ xhb, float* __restrict__ as_, float* __restrict__ ad_){
  __shared__ unsigned sxh[4][2][16*68];
  int wave = threadIdx.x>>6, lane = threadIdx.x&63;
  int base = blockIdx.x*128;
  int q = lane>>4, r = lane&15;
  int r0[2];
  r0[0] = base + wave*16;
  r0[1] = base + 64 + wave*16;
  if(r0[0] > N_NODES-16) r0[0] = N_NODES-16;
  if(r0[1] > N_NODES-16) r0[1] = N_NODES-16;
  v8bf av[2][4];
  #pragma unroll
  for(int tt=0;tt<2;++tt){
    const unsigned short* hrow = h16 + (size_t)(r0[tt] + r)*HID;
    #pragma unroll
    for(int kb=0;kb<4;++kb)
      av[tt][kb] = *(const v8bf*)(hrow + kb*32 + q*8);
  }
  v4f acc[2][8];
  #pragma unroll
  for(int cg=0;cg<8;++cg){
    v4f a0 = {0.f,0.f,0.f,0.f}, a1 = {0.f,0.f,0.f,0.f};
    #pragma unroll
    for(int kb=0;kb<4;++kb){
      v8bf bhi = *(const v8bf*)(whi + ((kb*8+cg)*64 + lane)*8);
      a0 = __builtin_amdgcn_mfma_f32_16x16x32_bf16(av[0][kb], bhi, a0, 0,0,0);
      a1 = __builtin_amdgcn_mfma_f32_16x16x32_bf16(av[1][kb], bhi, a1, 0,0,0);
    }
    acc[0][cg]=a0; acc[1][cg]=a1;
  }
  v4f acc8[2] = {{0.f,0.f,0.f,0.f},{0.f,0.f,0.f,0.f}};
  #pragma unroll
  for(int kb=0;kb<4;++kb){
    v8bf bhi = *(const v8bf*)(whiE + (kb*64 + lane)*8);
    v8bf blo = *(const v8bf*)(wloE + (kb*64 + lane)*8);
    #pragma unroll
    for(int tt=0;tt<2;++tt){
      acc8[tt] = __builtin_amdgcn_mfma_f32_16x16x32_bf16(av[tt][kb], blo, acc8[tt], 0,0,0);
      acc8[tt] = __builtin_amdgcn_mfma_f32_16x16x32_bf16(av[tt][kb], bhi, acc8[tt], 0,0,0);
    }
  }
  // stage packed words in LDS (stride 68 words -> 2-way banking, free)
  #pragma unroll
  for(int tt=0;tt<2;++tt){
    #pragma unroll
    for(int m=0;m<4;++m){
      #pragma unroll
      for(int reg=0;reg<4;++reg){
        unsigned pack = (unsigned)f2bf_bits(acc[tt][2*m][reg]) | ((unsigned)f2bf_bits(acc[tt][2*m+1][reg])<<16);
        sxh[wave][tt][(q*4+reg)*68 + m*16 + r] = pack;
      }
    }
  }
  __syncthreads();
  // coalesced write-back: one full 256B row per instruction
  {
    int rr = lane>>4, c4 = lane&15;
    #pragma unroll
    for(int tt=0;tt<2;++tt){
      #pragma unroll
      for(int rg=0; rg<4; ++rg){
        int i = rg*4 + rr;
        uint4 v = *(const uint4*)&sxh[wave][tt][i*68 + c4*4];
        *(uint4*)(xhb + (size_t)(r0[tt] + i)*64 + c4*4) = v;
      }
    }
  }
  #pragma unroll
  for(int tt=0;tt<2;++tt){
    if(r < 4){
      #pragma unroll
      for(int reg=0;reg<4;++reg)
        as_[(size_t)(r0[tt] + q*4 + reg)*4 + r] = acc8[tt][reg];
    } else if(r < 8){
      #pragma unroll
      for(int reg=0;reg<4;++reg)
        ad_[(size_t)(r0[tt] + q*4 + reg)*4 + (r-4)] = acc8[tt][reg];
    }
  }
}

// wave-per-node. Phase A: parallel softmax anchored at self-logit; deg<=16 fast
// path. Phase B: half-wave uint2 gather (lane's 4 channels all in head l>>3).
// Epilogue: permuted folded BN + relu + bf16 residual; writes h16.
__global__ void k_aggr(const unsigned* __restrict__ xhb, const float* __restrict__ as_,
    const float* __restrict__ ad_, const float* __restrict__ ea_csr,
    const float* __restrict__ mebuf,
    const int* __restrict__ rowptr, const int* __restrict__ csr_src,
    const float* __restrict__ bnA_l, const float* __restrict__ bnS_l,
    unsigned* __restrict__ h16, int layer){
  __shared__ float lds_coef[4][MAXDEG*4];
  __shared__ int   lds_src[4][MAXDEG];
  int w = threadIdx.x>>6, lane = threadIdx.x&63;
  int node = blockIdx.x*4 + w;
  if(node >= N_NODES) return;
  int s = rowptr[node], e = rowptr[node+1];
  int deg = e - s;
  int l = lane&31, half = lane>>5, hh2 = l>>3;
  const uint2* xrow = (const uint2*)xhb;
  float a0,a1,a2,a3;

  if(deg <= MAXDEG){
    int eidx = lane>>2, h = lane&3;
    int li = layer*4+h;
    float mec0=mebuf[li], mec1=mebuf[16+li], mec2=mebuf[32+li], meb=mebuf[48+li];
    float ad_h = ad_[node*4+h];
    int j0 = eidx;
    float t0 = 0.f, g0 = 0.f;
    int s0 = node;
    bool v0 = (j0 < deg);
    if(v0){
      s0 = csr_src[s+j0];
      v4f qq = ((const v4f*)ea_csr)[s+j0];
      t0 = qq.x*mec0 + qq.y*mec1 + qq.z*mec2;
      g0 = lrelu(as_[s0*4+h] + ad_h + t0 + meb);
    }
    float ts, ds, inv;
    if(deg <= 16){
      ts = t0;
      ts += __shfl_xor(ts,4); ts += __shfl_xor(ts,8);
      ts += __shfl_xor(ts,16); ts += __shfl_xor(ts,32);
      float lt = (deg>0) ? ts/(float)deg + meb : 0.f;
      float al = lrelu(as_[node*4+h] + ad_h + lt);
      float e0 = v0 ? __expf(g0-al) : 0.f;
      ds = e0;
      ds += __shfl_xor(ds,4); ds += __shfl_xor(ds,8);
      ds += __shfl_xor(ds,16); ds += __shfl_xor(ds,32);
      inv = 1.f/(ds+1.f);
      lds_src[w][j0] = s0;
      lds_coef[w][j0*4+h] = e0*inv;
    } else {
      int j1 = 16+eidx;
      float t1 = 0.f, g1 = 0.f;
      int s1 = node;
      bool v1 = (j1 < deg);
      if(v1){
        s1 = csr_src[s+j1];
        v4f qq = ((const v4f*)ea_csr)[s+j1];
        t1 = qq.x*mec0 + qq.y*mec1 + qq.z*mec2;
        g1 = lrelu(as_[s1*4+h] + ad_h + t1 + meb);
      }
      ts = t0+t1;
      ts += __shfl_xor(ts,4); ts += __shfl_xor(ts,8);
      ts += __shfl_xor(ts,16); ts += __shfl_xor(ts,32);
      float lt = ts/(float)deg + meb;
      float al = lrelu(as_[node*4+h] + ad_h + lt);
      float e0 = v0 ? __expf(g0-al) : 0.f;
      float e1 = v1 ? __expf(g1-al) : 0.f;
      ds = e0+e1;
      ds += __shfl_xor(ds,4); ds += __shfl_xor(ds,8);
      ds += __shfl_xor(ds,16); ds += __shfl_xor(ds,32);
      inv = 1.f/(ds+1.f);
      if(h==0){ lds_src[w][j0]=s0; lds_src[w][j1]=s1; }
      lds_coef[w][j0*4+h] = e0*inv;
      lds_coef[w][j1*4+h] = e1*inv;
    }
    // ---- phase B ----
    float cs4 = __shfl(inv, hh2);
    uint2 su = xrow[(size_t)node*32 + l];
    int pdeg = (deg+3)&~3;
    a0=a1=a2=a3=0.f;
    for(int j=0;j<pdeg;j+=4){
      float ca = lds_coef[w][(j+half)*4+hh2];
      float cb = lds_coef[w][(j+2+half)*4+hh2];
      int sa = lds_src[w][j+half], sb = lds_src[w][j+2+half];
      uint2 ua = xrow[(size_t)sa*32+l];
      uint2 ub = xrow[(size_t)sb*32+l];
      a0 += ca*bflo(ua.x) + cb*bflo(ub.x);
      a1 += ca*bfhi(ua.x) + cb*bfhi(ub.x);
      a2 += ca*bflo(ua.y) + cb*bflo(ub.y);
      a3 += ca*bfhi(ua.y) + cb*bfhi(ub.y);
    }
    a0 += __shfl_xor(a0,32); a1 += __shfl_xor(a1,32);
    a2 += __shfl_xor(a2,32); a3 += __shfl_xor(a3,32);
    a0 += cs4*bflo(su.x); a1 += cs4*bfhi(su.x);
    a2 += cs4*bflo(su.y); a3 += cs4*bfhi(su.y);
  } else {
    int li = layer*4+hh2;
    float mec0=mebuf[li], mec1=mebuf[16+li], mec2=mebuf[32+li], meb=mebuf[48+li];
    float adv = ad_[node*4+hh2];
    float ts = 0.f;
    for(int j=s;j<e;++j){
      v4f qq = ((const v4f*)ea_csr)[j];
      ts += qq.x*mec0 + qq.y*mec1 + qq.z*mec2;
    }
    float al = lrelu(as_[node*4+hh2] + adv + ts/(float)deg + meb);
    float m = al, d = 1.f;
    uint2 su = xrow[(size_t)node*32 + l];
    float c0=bflo(su.x),c1=bfhi(su.x),c2=bflo(su.y),c3=bfhi(su.y);
    for(int j=s;j<e;++j){
      int sr = csr_src[j];
      v4f qq = ((const v4f*)ea_csr)[j];
      float b = lrelu(as_[sr*4+hh2] + adv + qq.x*mec0+qq.y*mec1+qq.z*mec2+meb);
      uint2 uv = xrow[(size_t)sr*32 + l];
      float nm = fmaxf(m,b);
      float sc = __expf(m-nm), eb = __expf(b-nm);
      d = d*sc + eb;
      c0 = c0*sc + eb*bflo(uv.x); c1 = c1*sc + eb*bfhi(uv.x);
      c2 = c2*sc + eb*bflo(uv.y); c3 = c3*sc + eb*bfhi(uv.y);
      m = nm;
    }
    float inv2 = 1.f/d;
    a0=c0*inv2; a1=c1*inv2; a2=c2*inv2; a3=c3*inv2;
  }

  if(half==0){
    const v4f* A4 = (const v4f*)bnA_l;
    const v4f* S4 = (const v4f*)bnS_l;
    v4f A = A4[l], S = S4[l];
    uint2 hr = ((const uint2*)h16)[(size_t)node*32 + l];
    float o0 = fmaxf(a0*A.x+S.x, 0.f) + bflo(hr.x);
    float o1 = fmaxf(a1*A.y+S.y, 0.f) + bfhi(hr.x);
    float o2 = fmaxf(a2*A.z+S.z, 0.f) + bflo(hr.y);
    float o3 = fmaxf(a3*A.w+S.w, 0.f) + bfhi(hr.y);
    uint2 p;
    p.x = (unsigned)f2bf_bits(o0) | ((unsigned)f2bf_bits(o1)<<16);
    p.y = (unsigned)f2bf_bits(o2) | ((unsigned)f2bf_bits(o3)<<16);
    ((uint2*)h16)[(size_t)node*32 + l] = p;
  }
}

// fused pool + head
__global__ void k_tail(const unsigned* __restrict__ h16, const int* __restrict__ batch,
   const float* __restrict__ gf,
   const float* __restrict__ gc_w, const float* __restrict__ gc_b,
   const float* __restrict__ gf1_w, const float* __restrict__ gf1_b,
   const float* __restrict__ gf2_w, const float* __restrict__ gf2_b,
   const float* __restrict__ p1_w, const float* __restrict__ p1_b,
   const float* __restrict__ p2_w, const float* __restrict__ p2_b,
   const float* __restrict__ p3_w, const float* __restrict__ p3_b,
   float* __restrict__ out){
  __shared__ float sg[384];
  __shared__ int sb[2];
  __shared__ float comb[192];
  __shared__ float hid1[64];
  __shared__ float r1[128];
  __shared__ float r2[64];
  int g = blockIdx.x, t = threadIdx.x;
  if(t < 2){
    int target = g + t;
    int lo=0, hi=N_NODES;
    while(lo<hi){ int mid=(lo+hi)>>1; if(batch[mid] < target) lo=mid+1; else hi=mid; }
    sb[t]=lo;
  }
  __syncthreads();
  {
    int s = sb[0], e = sb[1];
    int u = ((t>>5)<<4) + (t&15);
    int hiflag = (t>>4)&1;
    float sum=0.f, mx=-3.4e38f;
    for(int i=s;i<e;++i){
      unsigned uv = h16[(size_t)i*64 + u];
      float v = hiflag ? bfhi(uv) : bflo(uv);
      sum+=v; mx=fmaxf(mx,v);
    }
    int cnt = e-s;
    float meanv = sum / (float)(cnt>1?cnt:1);
    if(cnt==0) mx=0.f;
    sg[t] = meanv;
    sg[128+t] = mx;
    sg[256+t] = sum;
  }
  if(t<64){
    float a = gf1_b[t];
    #pragma unroll
    for(int i=0;i<10;++i) a += gf[g*10+i]*gf1_w[i*64+t];
    hid1[t] = fmaxf(a,0.f);
  }
  __syncthreads();
  if(t<64){
    float a = gf2_b[t];
    for(int k=0;k<64;++k) a += hid1[k]*gf2_w[k*64+t];
    comb[128+t] = a;
  }
  {
    float a = gc_b[t];
    for(int k=0;k<384;++k) a += sg[k]*gc_w[k*128+t];
    comb[t] = fmaxf(a,0.f);
  }
  __syncthreads();
  {
    float a = p1_b[t];
    for(int k=0;k<192;++k) a += comb[k]*p1_w[k*128+t];
    r1[t] = fmaxf(a,0.f);
  }
  __syncthreads();
  if(t<64){
    float a = p2_b[t];
    for(int k=0;k<128;++k) a += r1[k]*p2_w[k*64+t];
    r2[t] = fmaxf(a,0.f);
  }
  __syncthreads();
  if(t<TOUT){
    float a = p3_b[t];
    for(int k=0;k<64;++k) a += r2[k]*p3_w[k*TOUT+t];
    out[g*TOUT+t] = a;
  }
}

extern "C" void kernel_launch(void* const* d_in, const int* in_sizes, int n_in,
                              void* d_out, int out_size, void* d_ws, size_t ws_size,
                              hipStream_t stream){
  (void)in_sizes; (void)n_in; (void)out_size; (void)ws_size;
  const float* x        = (const float*)d_in[0];
  const int*   ei       = (const int*)d_in[1];
  const float* ea       = (const float*)d_in[2];
  const int*   batch    = (const int*)d_in[3];
  const float* gfin     = (const float*)d_in[4];
  const float* node_w   = (const float*)d_in[5];
  const float* node_b   = (const float*)d_in[6];
  const float* edge_w   = (const float*)d_in[7];
  const float* edge_b   = (const float*)d_in[8];
  const float* gat_lin_w  = (const float*)d_in[9];
  const float* gat_edge_w = (const float*)d_in[10];
  const float* att_src  = (const float*)d_in[11];
  const float* att_dst  = (const float*)d_in[12];
  const float* att_edge = (const float*)d_in[13];
  const float* gat_bias = (const float*)d_in[14];
  const float* bn_gamma = (const float*)d_in[15];
  const float* bn_beta  = (const float*)d_in[16];
  const float* bn_mean  = (const float*)d_in[17];
  const float* bn_var   = (const float*)d_in[18];
  const float* gc_w = (const float*)d_in[19];
  const float* gc_b = (const float*)d_in[20];
  const float* gf1_w = (const float*)d_in[21];
  const float* gf1_b = (const float*)d_in[22];
  const float* gf2_w = (const float*)d_in[23];
  const float* gf2_b = (const float*)d_in[24];
  const float* p1_w = (const float*)d_in[25];
  const float* p1_b = (const float*)d_in[26];
  const float* p2_w = (const float*)d_in[27];
  const float* p2_b = (const float*)d_in[28];
  const float* p3_w = (const float*)d_in[29];
  const float* p3_b = (const float*)d_in[30];
  float* out = (float*)d_out;

  char* w = (char*)d_ws;
  size_t o = 0;
  auto carve = [&](size_t bytes)->char*{
    char* p = w + o; o += (bytes + 255) & ~(size_t)255; return p;
  };
  unsigned* xhb = (unsigned*)carve((size_t)N_NODES*64*4);
  unsigned* h16 = (unsigned*)carve((size_t)N_NODES*64*4);
  float* ea_csr = (float*)carve((size_t)N_EDGES*4*4);
  float* as_    = (float*)carve((size_t)N_NODES*4*4);
  float* ad_    = (float*)carve((size_t)N_NODES*4*4);
  int* deg      = (int*)carve((size_t)N_NODES*4);
  int* rowptr   = (int*)carve((size_t)(N_NODES+1)*4);
  int* fill     = (int*)carve((size_t)N_NODES*4);
  int* csr_src  = (int*)carve((size_t)N_EDGES*4);
  int* part     = (int*)carve(1024*4);
  float* mebuf  = (float*)carve(64*4);
  float* bnA    = (float*)carve((size_t)NLAYER*HID*4);
  float* bnS    = (float*)carve((size_t)NLAYER*HID*4);
  unsigned short* whi = (unsigned short*)carve(65536*2);
  unsigned short* whiE = (unsigned short*)carve(8192*2);
  unsigned short* wloE = (unsigned short*)carve(8192*2);

  // setup: prep + w_ext + wswz + zero(deg,fill)
  int zb = (N_NODES+255)/256;
  k_setup<<<1 + 1024 + 256 + zb, 256, 0, stream>>>(gat_edge_w, att_edge, edge_w, edge_b,
        gat_bias, bn_gamma, bn_beta, bn_mean, bn_var,
        gat_lin_w, att_src, att_dst, mebuf, bnA, bnS, whiE, wloE, whi, deg, fill);
  k_init<<<N_NODES/4 + (N_EDGES+255)/256, 256, 0, stream>>>(x, node_w, node_b, h16, ei, deg);
  k_scan1<<<NB,256,0,stream>>>(deg, part);
  k_scan3<<<NB,256,0,stream>>>(deg, part, rowptr);
  k_fill<<<(N_EDGES+255)/256,256,0,stream>>>(ei, ea, rowptr, fill, csr_src, ea_csr);

  for(int l=0;l<NLAYER;++l){
    k_gemm<<<(N_NODES+127)/128,256,0,stream>>>((const unsigned short*)h16,
        whi + l*16384, whiE + l*2048, wloE + l*2048,
        xhb, as_, ad_);
    k_aggr<<<(N_NODES+3)/4,256,0,stream>>>(xhb, as_, ad_, ea_csr, mebuf,
        rowptr, csr_src, bnA + l*128, bnS + l*128, h16, l);
  }

  k_tail<<<N_GRAPHS,128,0,stream>>>(h16, batch, gfin, gc_w, gc_b, gf1_w, gf1_b,
        gf2_w, gf2_b, p1_w, p1_b, p2_w, p2_b, p3_w, p3_b, out);
}

// Round 18
// 494.972 us; speedup vs baseline: 1.9706x; 1.0523x over previous
//
#include <hip/hip_runtime.h>

#define N_NODES 100000
#define N_EDGES 400000
#define N_GRAPHS 2048
#define HID 128
#define NLAYER 4
#define TOUT 5
#define EPSV 1e-5f
#define SLOPE 0.2f
#define MAXDEG 32
#define NB 98   // (N_NODES+1023)/1024
#define GEMM_BLOCKS 782  // (N_NODES+127)/128

typedef float v4f __attribute__((ext_vector_type(4)));
typedef __bf16 v8bf __attribute__((ext_vector_type(8)));

static __device__ __forceinline__ unsigned short f2bf_bits(float f){
  unsigned u = __builtin_bit_cast(unsigned, f);
  unsigned r = u + 0x7fffu + ((u >> 16) & 1u);
  return (unsigned short)(r >> 16);
}
static __device__ __forceinline__ float bfbits2f(unsigned short s){
  unsigned u = ((unsigned)s) << 16;
  return __builtin_bit_cast(float, u);
}
static __device__ __forceinline__ float bflo(unsigned u){
  return __builtin_bit_cast(float, u << 16);
}
static __device__ __forceinline__ float bfhi(unsigned u){
  return __builtin_bit_cast(float, u & 0xffff0000u);
}
static __device__ __forceinline__ float lrelu(float v){
  return v>0.f ? v : SLOPE*v;
}

// Physical bf16 layout (head-aligned pairing):
//   word u (0..63): b=u>>4, r=u&15 -> holds channels (b*32+r [lo], b*32+16+r [hi]).
//   Lane l (words 2l,2l+1) is entirely head l>>3.
//   contraction position for channel k: kp = (k>>5)*32 + (k&15)*2 + ((k>>4)&1).

// merged setup:
//  blocks 0..15      : mebuf direct (wave-per-output, parallel)
//  block  16         : BN fold
//  blocks 17..1040   : w_ext (split hi/lo)
//  blocks 1041..1296 : wswz (single bf16 W)
//  blocks 1297..1687 : zero deg/fill
//  blocks 1688..     : hinit
__global__ void k_setup(const float* __restrict__ gat_edge_w, const float* __restrict__ att_edge,
                        const float* __restrict__ edge_w, const float* __restrict__ edge_b,
                        const float* __restrict__ gat_bias, const float* __restrict__ gamma,
                        const float* __restrict__ beta, const float* __restrict__ mean,
                        const float* __restrict__ var, const float* __restrict__ gat_lin_w,
                        const float* __restrict__ att_src, const float* __restrict__ att_dst,
                        const float* __restrict__ x, const float* __restrict__ nw,
                        const float* __restrict__ nb, unsigned* __restrict__ h16,
                        float* __restrict__ mebuf, float* __restrict__ bnA, float* __restrict__ bnS,
                        unsigned short* __restrict__ whiE, unsigned short* __restrict__ wloE,
                        unsigned short* __restrict__ whi,
                        int* __restrict__ deg, int* __restrict__ fill){
  int bid = blockIdx.x, t = threadIdx.x;
  if(bid < 16){
    // mebuf[o], o = bid*4 + wave; o<48: edge_w row f=o>>4; o>=48: edge_b
    int wv = t>>6, lane = t&63;
    int o = bid*4 + wv;
    int li = (o<48)? (o&15) : (o-48);
    int f = o>>4;
    int l = li>>2, hh = li&3;
    int c = lane&31, kk = lane>>5;
    float at_c = att_edge[l*128 + hh*32 + c];
    float acc = 0.f;
    #pragma unroll 8
    for(int t2=0; t2<64; ++t2){
      int k = kk*64 + t2;
      float wk = (o<48)? edge_w[f*128+k] : edge_b[k];
      acc += wk * gat_edge_w[l*16384 + k*128 + hh*32 + c];
    }
    acc *= at_c;
    acc += __shfl_xor(acc,1); acc += __shfl_xor(acc,2); acc += __shfl_xor(acc,4);
    acc += __shfl_xor(acc,8); acc += __shfl_xor(acc,16); acc += __shfl_xor(acc,32);
    if(lane==0) mebuf[o] = acc;
  } else if(bid == 16){
    for(int i=t; i<NLAYER*HID; i+=256){
      int l_ = i>>7, pos = i&127, lane = pos>>2, j = pos&3;
      int ch = ((lane>>3)<<5) + ((lane&7)<<1) + ((j&1)<<4) + (j>>1);
      int src = l_*128 + ch;
      float A = gamma[src]*rsqrtf(var[src]+EPSV);
      bnA[i] = A;
      bnS[i] = (gat_bias[src]-mean[src])*A + beta[src];
    }
  } else if(bid <= 1040){
    int wave = t>>6, lane = t&63;
    int i = (bid-17)*8 + wave*2 + (lane>>5);   // 0..8191
    int l_ = i>>11, rest = i&2047, kp = rest>>4, col = rest&15;
    int sub = lane&31;
    float val = 0.f;
    if(col < 8){
      int h_ = col&3, isdst = col>>2;
      int ch = ((kp>>5)<<5) + ((kp&1)<<4) + ((kp&31)>>1);
      const float* at = (isdst? att_dst : att_src);
      val = gat_lin_w[l_*16384 + ch*128 + h_*32 + sub] * at[l_*128 + h_*32 + sub];
    }
    val += __shfl_xor(val,1); val += __shfl_xor(val,2); val += __shfl_xor(val,4);
    val += __shfl_xor(val,8); val += __shfl_xor(val,16);
    if(sub == 0){
      unsigned short hi = f2bf_bits(val);
      unsigned short lo = f2bf_bits(val - bfbits2f(hi));
      int kb=kp>>5, quad=(kp>>3)&3, jj=kp&7, lane2=quad*16+col;
      int dst = ((l_*4+kb)*64 + lane2)*8 + jj;
      whiE[dst]=hi; wloE[dst]=lo;
    }
  } else if(bid <= 1296){
    int tg = (bid-1041)*256 + t;              // 0..65535 == dst index
    int base = tg>>9, off = tg&511;
    int l = base>>5, kb=(base>>3)&3, cg=base&7;
    int lane = off>>3, j = off&7;
    int quad = lane>>4, r = lane&15;
    int kp = kb*32 + quad*8 + j;
    int k = ((kp>>5)<<5) | ((kp&1)<<4) | ((kp&31)>>1);
    whi[tg] = f2bf_bits(gat_lin_w[l*16384 + k*128 + cg*16 + r]);
  } else if(bid <= 1687){
    int tg = (bid-1297)*256 + t;
    if(tg < N_NODES){ deg[tg]=0; fill[tg]=0; }
  } else {
    int node = (bid-1688)*4 + (t>>6);
    int c = t&63;
    int ch = ((c>>4)<<5) + (c&15);
    float a0 = nb[ch], a1 = nb[ch+16];
    #pragma unroll
    for(int f=0; f<7; ++f){
      float xv = x[node*7+f];
      a0 += xv*nw[f*HID+ch];
      a1 += xv*nw[f*HID+ch+16];
    }
    unsigned p = (unsigned)f2bf_bits(a0) | ((unsigned)f2bf_bits(a1)<<16);
    h16[(size_t)node*64 + c] = p;
  }
}

// deg count only (after zeroing in k_setup)
__global__ void k_deg(const int* __restrict__ ei, int* __restrict__ deg){
  int e = blockIdx.x*256 + threadIdx.x;
  if(e < N_EDGES) atomicAdd(&deg[ei[N_EDGES+e]], 1);
}

// scan phase 1: per-chunk sums
__global__ void k_scan1(const int* __restrict__ deg, int* __restrict__ part){
  __shared__ int s[256];
  int t=threadIdx.x; int base = blockIdx.x*1024 + t*4;
  int sum=0;
  #pragma unroll
  for(int j=0;j<4;++j){ int i=base+j; sum += (i<N_NODES)? deg[i]:0; }
  s[t]=sum; __syncthreads();
  for(int off=128; off>0; off>>=1){ if(t<off) s[t]+=s[t+off]; __syncthreads(); }
  if(t==0) part[blockIdx.x]=s[0];
}
// scan phase 2+3 fused
__global__ void k_scan3(const int* __restrict__ deg, const int* __restrict__ part,
                        int* __restrict__ rowptr){
  __shared__ int s[256];
  int t=threadIdx.x, b=blockIdx.x;
  int g = 0, tot = 0;
  for(int i=0;i<NB;++i){ int v = part[i]; g += (i<b)? v : 0; tot += v; }
  if(b==0 && t==0) rowptr[N_NODES]=tot;
  int base = b*1024 + t*4;
  int v[4]; int sum=0; int pre[4];
  #pragma unroll
  for(int j=0;j<4;++j){ int i=base+j; v[j]=(i<N_NODES)?deg[i]:0; pre[j]=sum; sum+=v[j]; }
  s[t]=sum; __syncthreads();
  for(int off=1; off<256; off<<=1){
    int xv = (t>=off)? s[t-off]:0; __syncthreads();
    s[t]+=xv; __syncthreads();
  }
  int toff = (t>0)? s[t-1]:0;
  #pragma unroll
  for(int j=0;j<4;++j){ int i=base+j; if(i<N_NODES) rowptr[i]=g+toff+pre[j]; }
}

// xh = h16 @ W[l], 2 row-tiles per wave; as_/ad_ via split-precision w_ext tile.
// LDS-staged coalesced stores. Layer-0 launch carries extra blocks that build
// the CSR (fill) — uniform per-block branch, no data conflicts.
__global__ void k_gemm(const unsigned short* __restrict__ h16,
                       const unsigned short* __restrict__ whi,
                       const unsigned short* __restrict__ whiE,
                       const unsigned short* __restrict__ wloE,
                       unsigned* __restrict__ xhb, float* __restrict__ as_, float* __restrict__ ad_,
                       const int* __restrict__ ei, const float* __restrict__ ea,
                       const int* __restrict__ rowptr, int* __restrict__ fill,
                       int* __restrict__ csr_src, float* __restrict__ ea_csr){
  if(blockIdx.x >= GEMM_BLOCKS){
    int e = (blockIdx.x - GEMM_BLOCKS)*256 + threadIdx.x;
    if(e < N_EDGES){
      int dst = ei[N_EDGES+e];
      int pos = rowptr[dst] + atomicAdd(&fill[dst],1);
      csr_src[pos] = ei[e];
      v4f q = {ea[e*3], ea[e*3+1], ea[e*3+2], 0.f};
      ((v4f*)ea_csr)[pos] = q;
    }
    return;
  }
  __shared__ unsigned sxh[4][2][16*68];
  int wave = threadIdx.x>>6, lane = threadIdx.x&63;
  int base = blockIdx.x*128;
  int q = lane>>4, r = lane&15;
  int r0[2];
  r0[0] = base + wave*16;
  r0[1] = base + 64 + wave*16;
  if(r0[0] > N_NODES-16) r0[0] = N_NODES-16;
  if(r0[1] > N_NODES-16) r0[1] = N_NODES-16;
  v8bf av[2][4];
  #pragma unroll
  for(int tt=0;tt<2;++tt){
    const unsigned short* hrow = h16 + (size_t)(r0[tt] + r)*HID;
    #pragma unroll
    for(int kb=0;kb<4;++kb)
      av[tt][kb] = *(const v8bf*)(hrow + kb*32 + q*8);
  }
  v4f acc[2][8];
  #pragma unroll
  for(int cg=0;cg<8;++cg){
    v4f a0 = {0.f,0.f,0.f,0.f}, a1 = {0.f,0.f,0.f,0.f};
    #pragma unroll
    for(int kb=0;kb<4;++kb){
      v8bf bhi = *(const v8bf*)(whi + ((kb*8+cg)*64 + lane)*8);
      a0 = __builtin_amdgcn_mfma_f32_16x16x32_bf16(av[0][kb], bhi, a0, 0,0,0);
      a1 = __builtin_amdgcn_mfma_f32_16x16x32_bf16(av[1][kb], bhi, a1, 0,0,0);
    }
    acc[0][cg]=a0; acc[1][cg]=a1;
  }
  v4f acc8[2] = {{0.f,0.f,0.f,0.f},{0.f,0.f,0.f,0.f}};
  #pragma unroll
  for(int kb=0;kb<4;++kb){
    v8bf bhi = *(const v8bf*)(whiE + (kb*64 + lane)*8);
    v8bf blo = *(const v8bf*)(wloE + (kb*64 + lane)*8);
    #pragma unroll
    for(int tt=0;tt<2;++tt){
      acc8[tt] = __builtin_amdgcn_mfma_f32_16x16x32_bf16(av[tt][kb], blo, acc8[tt], 0,0,0);
      acc8[tt] = __builtin_amdgcn_mfma_f32_16x16x32_bf16(av[tt][kb], bhi, acc8[tt], 0,0,0);
    }
  }
  #pragma unroll
  for(int tt=0;tt<2;++tt){
    #pragma unroll
    for(int m=0;m<4;++m){
      #pragma unroll
      for(int reg=0;reg<4;++reg){
        unsigned pack = (unsigned)f2bf_bits(acc[tt][2*m][reg]) | ((unsigned)f2bf_bits(acc[tt][2*m+1][reg])<<16);
        sxh[wave][tt][(q*4+reg)*68 + m*16 + r] = pack;
      }
    }
  }
  __syncthreads();
  {
    int rr = lane>>4, c4 = lane&15;
    #pragma unroll
    for(int tt=0;tt<2;++tt){
      #pragma unroll
      for(int rg=0; rg<4; ++rg){
        int i = rg*4 + rr;
        uint4 v = *(const uint4*)&sxh[wave][tt][i*68 + c4*4];
        *(uint4*)(xhb + (size_t)(r0[tt] + i)*64 + c4*4) = v;
      }
    }
  }
  #pragma unroll
  for(int tt=0;tt<2;++tt){
    if(r < 4){
      #pragma unroll
      for(int reg=0;reg<4;++reg)
        as_[(size_t)(r0[tt] + q*4 + reg)*4 + r] = acc8[tt][reg];
    } else if(r < 8){
      #pragma unroll
      for(int reg=0;reg<4;++reg)
        ad_[(size_t)(r0[tt] + q*4 + reg)*4 + (r-4)] = acc8[tt][reg];
    }
  }
}

// wave-per-node. Phase A: parallel softmax anchored at self-logit; deg<=16 fast
// path. Phase B: half-wave uint2 gather (lane's 4 channels all in head l>>3).
// Epilogue: permuted folded BN + relu + bf16 residual; writes h16.
__global__ void k_aggr(const unsigned* __restrict__ xhb, const float* __restrict__ as_,
    const float* __restrict__ ad_, const float* __restrict__ ea_csr,
    const float* __restrict__ mebuf,
    const int* __restrict__ rowptr, const int* __restrict__ csr_src,
    const float* __restrict__ bnA_l, const float* __restrict__ bnS_l,
    unsigned* __restrict__ h16, int layer){
  __shared__ float lds_coef[4][MAXDEG*4];
  __shared__ int   lds_src[4][MAXDEG];
  int w = threadIdx.x>>6, lane = threadIdx.x&63;
  int node = blockIdx.x*4 + w;
  if(node >= N_NODES) return;
  int s = rowptr[node], e = rowptr[node+1];
  int deg = e - s;
  int l = lane&31, half = lane>>5, hh2 = l>>3;
  const uint2* xrow = (const uint2*)xhb;
  float a0,a1,a2,a3;

  if(deg <= MAXDEG){
    int eidx = lane>>2, h = lane&3;
    int li = layer*4+h;
    float mec0=mebuf[li], mec1=mebuf[16+li], mec2=mebuf[32+li], meb=mebuf[48+li];
    float ad_h = ad_[node*4+h];
    int j0 = eidx;
    float t0 = 0.f, g0 = 0.f;
    int s0 = node;
    bool v0 = (j0 < deg);
    if(v0){
      s0 = csr_src[s+j0];
      v4f qq = ((const v4f*)ea_csr)[s+j0];
      t0 = qq.x*mec0 + qq.y*mec1 + qq.z*mec2;
      g0 = lrelu(as_[s0*4+h] + ad_h + t0 + meb);
    }
    float ts, ds, inv;
    if(deg <= 16){
      ts = t0;
      ts += __shfl_xor(ts,4); ts += __shfl_xor(ts,8);
      ts += __shfl_xor(ts,16); ts += __shfl_xor(ts,32);
      float lt = (deg>0) ? ts/(float)deg + meb : 0.f;
      float al = lrelu(as_[node*4+h] + ad_h + lt);
      float e0 = v0 ? __expf(g0-al) : 0.f;
      ds = e0;
      ds += __shfl_xor(ds,4); ds += __shfl_xor(ds,8);
      ds += __shfl_xor(ds,16); ds += __shfl_xor(ds,32);
      inv = 1.f/(ds+1.f);
      lds_src[w][j0] = s0;
      lds_coef[w][j0*4+h] = e0*inv;
    } else {
      int j1 = 16+eidx;
      float t1 = 0.f, g1 = 0.f;
      int s1 = node;
      bool v1 = (j1 < deg);
      if(v1){
        s1 = csr_src[s+j1];
        v4f qq = ((const v4f*)ea_csr)[s+j1];
        t1 = qq.x*mec0 + qq.y*mec1 + qq.z*mec2;
        g1 = lrelu(as_[s1*4+h] + ad_h + t1 + meb);
      }
      ts = t0+t1;
      ts += __shfl_xor(ts,4); ts += __shfl_xor(ts,8);
      ts += __shfl_xor(ts,16); ts += __shfl_xor(ts,32);
      float lt = ts/(float)deg + meb;
      float al = lrelu(as_[node*4+h] + ad_h + lt);
      float e0 = v0 ? __expf(g0-al) : 0.f;
      float e1 = v1 ? __expf(g1-al) : 0.f;
      ds = e0+e1;
      ds += __shfl_xor(ds,4); ds += __shfl_xor(ds,8);
      ds += __shfl_xor(ds,16); ds += __shfl_xor(ds,32);
      inv = 1.f/(ds+1.f);
      if(h==0){ lds_src[w][j0]=s0; lds_src[w][j1]=s1; }
      lds_coef[w][j0*4+h] = e0*inv;
      lds_coef[w][j1*4+h] = e1*inv;
    }
    // ---- phase B ----
    float cs4 = __shfl(inv, hh2);
    uint2 su = xrow[(size_t)node*32 + l];
    int pdeg = (deg+3)&~3;
    a0=a1=a2=a3=0.f;
    for(int j=0;j<pdeg;j+=4){
      float ca = lds_coef[w][(j+half)*4+hh2];
      float cb = lds_coef[w][(j+2+half)*4+hh2];
      int sa = lds_src[w][j+half], sb = lds_src[w][j+2+half];
      uint2 ua = xrow[(size_t)sa*32+l];
      uint2 ub = xrow[(size_t)sb*32+l];
      a0 += ca*bflo(ua.x) + cb*bflo(ub.x);
      a1 += ca*bfhi(ua.x) + cb*bfhi(ub.x);
      a2 += ca*bflo(ua.y) + cb*bflo(ub.y);
      a3 += ca*bfhi(ua.y) + cb*bfhi(ub.y);
    }
    a0 += __shfl_xor(a0,32); a1 += __shfl_xor(a1,32);
    a2 += __shfl_xor(a2,32); a3 += __shfl_xor(a3,32);
    a0 += cs4*bflo(su.x); a1 += cs4*bfhi(su.x);
    a2 += cs4*bflo(su.y); a3 += cs4*bfhi(su.y);
  } else {
    int li = layer*4+hh2;
    float mec0=mebuf[li], mec1=mebuf[16+li], mec2=mebuf[32+li], meb=mebuf[48+li];
    float adv = ad_[node*4+hh2];
    float ts = 0.f;
    for(int j=s;j<e;++j){
      v4f qq = ((const v4f*)ea_csr)[j];
      ts += qq.x*mec0 + qq.y*mec1 + qq.z*mec2;
    }
    float al = lrelu(as_[node*4+hh2] + adv + ts/(float)deg + meb);
    float m = al, d = 1.f;
    uint2 su = xrow[(size_t)node*32 + l];
    float c0=bflo(su.x),c1=bfhi(su.x),c2=bflo(su.y),c3=bfhi(su.y);
    for(int j=s;j<e;++j){
      int sr = csr_src[j];
      v4f qq = ((const v4f*)ea_csr)[j];
      float b = lrelu(as_[sr*4+hh2] + adv + qq.x*mec0+qq.y*mec1+qq.z*mec2+meb);
      uint2 uv = xrow[(size_t)sr*32 + l];
      float nm = fmaxf(m,b);
      float sc = __expf(m-nm), eb = __expf(b-nm);
      d = d*sc + eb;
      c0 = c0*sc + eb*bflo(uv.x); c1 = c1*sc + eb*bfhi(uv.x);
      c2 = c2*sc + eb*bflo(uv.y); c3 = c3*sc + eb*bfhi(uv.y);
      m = nm;
    }
    float inv2 = 1.f/d;
    a0=c0*inv2; a1=c1*inv2; a2=c2*inv2; a3=c3*inv2;
  }

  if(half==0){
    const v4f* A4 = (const v4f*)bnA_l;
    const v4f* S4 = (const v4f*)bnS_l;
    v4f A = A4[l], S = S4[l];
    uint2 hr = ((const uint2*)h16)[(size_t)node*32 + l];
    float o0 = fmaxf(a0*A.x+S.x, 0.f) + bflo(hr.x);
    float o1 = fmaxf(a1*A.y+S.y, 0.f) + bfhi(hr.x);
    float o2 = fmaxf(a2*A.z+S.z, 0.f) + bflo(hr.y);
    float o3 = fmaxf(a3*A.w+S.w, 0.f) + bfhi(hr.y);
    uint2 p;
    p.x = (unsigned)f2bf_bits(o0) | ((unsigned)f2bf_bits(o1)<<16);
    p.y = (unsigned)f2bf_bits(o2) | ((unsigned)f2bf_bits(o3)<<16);
    ((uint2*)h16)[(size_t)node*32 + l] = p;
  }
}

// fused pool + head
__global__ void k_tail(const unsigned* __restrict__ h16, const int* __restrict__ batch,
   const float* __restrict__ gf,
   const float* __restrict__ gc_w, const float* __restrict__ gc_b,
   const float* __restrict__ gf1_w, const float* __restrict__ gf1_b,
   const float* __restrict__ gf2_w, const float* __restrict__ gf2_b,
   const float* __restrict__ p1_w, const float* __restrict__ p1_b,
   const float* __restrict__ p2_w, const float* __restrict__ p2_b,
   const float* __restrict__ p3_w, const float* __restrict__ p3_b,
   float* __restrict__ out){
  __shared__ float sg[384];
  __shared__ int sb[2];
  __shared__ float comb[192];
  __shared__ float hid1[64];
  __shared__ float r1[128];
  __shared__ float r2[64];
  int g = blockIdx.x, t = threadIdx.x;
  if(t < 2){
    int target = g + t;
    int lo=0, hi=N_NODES;
    while(lo<hi){ int mid=(lo+hi)>>1; if(batch[mid] < target) lo=mid+1; else hi=mid; }
    sb[t]=lo;
  }
  __syncthreads();
  {
    int s = sb[0], e = sb[1];
    int u = ((t>>5)<<4) + (t&15);
    int hiflag = (t>>4)&1;
    float sum=0.f, mx=-3.4e38f;
    for(int i=s;i<e;++i){
      unsigned uv = h16[(size_t)i*64 + u];
      float v = hiflag ? bfhi(uv) : bflo(uv);
      sum+=v; mx=fmaxf(mx,v);
    }
    int cnt = e-s;
    float meanv = sum / (float)(cnt>1?cnt:1);
    if(cnt==0) mx=0.f;
    sg[t] = meanv;
    sg[128+t] = mx;
    sg[256+t] = sum;
  }
  if(t<64){
    float a = gf1_b[t];
    #pragma unroll
    for(int i=0;i<10;++i) a += gf[g*10+i]*gf1_w[i*64+t];
    hid1[t] = fmaxf(a,0.f);
  }
  __syncthreads();
  if(t<64){
    float a = gf2_b[t];
    for(int k=0;k<64;++k) a += hid1[k]*gf2_w[k*64+t];
    comb[128+t] = a;
  }
  {
    float a = gc_b[t];
    for(int k=0;k<384;++k) a += sg[k]*gc_w[k*128+t];
    comb[t] = fmaxf(a,0.f);
  }
  __syncthreads();
  {
    float a = p1_b[t];
    for(int k=0;k<192;++k) a += comb[k]*p1_w[k*128+t];
    r1[t] = fmaxf(a,0.f);
  }
  __syncthreads();
  if(t<64){
    float a = p2_b[t];
    for(int k=0;k<128;++k) a += r1[k]*p2_w[k*64+t];
    r2[t] = fmaxf(a,0.f);
  }
  __syncthreads();
  if(t<TOUT){
    float a = p3_b[t];
    for(int k=0;k<64;++k) a += r2[k]*p3_w[k*TOUT+t];
    out[g*TOUT+t] = a;
  }
}

extern "C" void kernel_launch(void* const* d_in, const int* in_sizes, int n_in,
                              void* d_out, int out_size, void* d_ws, size_t ws_size,
                              hipStream_t stream){
  (void)in_sizes; (void)n_in; (void)out_size; (void)ws_size;
  const float* x        = (const float*)d_in[0];
  const int*   ei       = (const int*)d_in[1];
  const float* ea       = (const float*)d_in[2];
  const int*   batch    = (const int*)d_in[3];
  const float* gfin     = (const float*)d_in[4];
  const float* node_w   = (const float*)d_in[5];
  const float* node_b   = (const float*)d_in[6];
  const float* edge_w   = (const float*)d_in[7];
  const float* edge_b   = (const float*)d_in[8];
  const float* gat_lin_w  = (const float*)d_in[9];
  const float* gat_edge_w = (const float*)d_in[10];
  const float* att_src  = (const float*)d_in[11];
  const float* att_dst  = (const float*)d_in[12];
  const float* att_edge = (const float*)d_in[13];
  const float* gat_bias = (const float*)d_in[14];
  const float* bn_gamma = (const float*)d_in[15];
  const float* bn_beta  = (const float*)d_in[16];
  const float* bn_mean  = (const float*)d_in[17];
  const float* bn_var   = (const float*)d_in[18];
  const float* gc_w = (const float*)d_in[19];
  const float* gc_b = (const float*)d_in[20];
  const float* gf1_w = (const float*)d_in[21];
  const float* gf1_b = (const float*)d_in[22];
  const float* gf2_w = (const float*)d_in[23];
  const float* gf2_b = (const float*)d_in[24];
  const float* p1_w = (const float*)d_in[25];
  const float* p1_b = (const float*)d_in[26];
  const float* p2_w = (const float*)d_in[27];
  const float* p2_b = (const float*)d_in[28];
  const float* p3_w = (const float*)d_in[29];
  const float* p3_b = (const float*)d_in[30];
  float* out = (float*)d_out;

  char* w = (char*)d_ws;
  size_t o = 0;
  auto carve = [&](size_t bytes)->char*{
    char* p = w + o; o += (bytes + 255) & ~(size_t)255; return p;
  };
  unsigned* xhb = (unsigned*)carve((size_t)N_NODES*64*4);
  unsigned* h16 = (unsigned*)carve((size_t)N_NODES*64*4);
  float* ea_csr = (float*)carve((size_t)N_EDGES*4*4);
  float* as_    = (float*)carve((size_t)N_NODES*4*4);
  float* ad_    = (float*)carve((size_t)N_NODES*4*4);
  int* deg      = (int*)carve((size_t)N_NODES*4);
  int* rowptr   = (int*)carve((size_t)(N_NODES+1)*4);
  int* fill     = (int*)carve((size_t)N_NODES*4);
  int* csr_src  = (int*)carve((size_t)N_EDGES*4);
  int* part     = (int*)carve(1024*4);
  float* mebuf  = (float*)carve(64*4);
  float* bnA    = (float*)carve((size_t)NLAYER*HID*4);
  float* bnS    = (float*)carve((size_t)NLAYER*HID*4);
  unsigned short* whi = (unsigned short*)carve(65536*2);
  unsigned short* whiE = (unsigned short*)carve(8192*2);
  unsigned short* wloE = (unsigned short*)carve(8192*2);

  // setup: mebuf + BNfold + w_ext + wswz + zero(deg,fill) + hinit
  k_setup<<<1688 + N_NODES/4, 256, 0, stream>>>(gat_edge_w, att_edge, edge_w, edge_b,
        gat_bias, bn_gamma, bn_beta, bn_mean, bn_var,
        gat_lin_w, att_src, att_dst, x, node_w, node_b, h16,
        mebuf, bnA, bnS, whiE, wloE, whi, deg, fill);
  k_deg<<<(N_EDGES+255)/256, 256, 0, stream>>>(ei, deg);
  k_scan1<<<NB,256,0,stream>>>(deg, part);
  k_scan3<<<NB,256,0,stream>>>(deg, part, rowptr);

  for(int l=0;l<NLAYER;++l){
    int gb = (l==0) ? GEMM_BLOCKS + (N_EDGES+255)/256 : GEMM_BLOCKS;
    k_gemm<<<gb,256,0,stream>>>((const unsigned short*)h16,
        whi + l*16384, whiE + l*2048, wloE + l*2048,
        xhb, as_, ad_, ei, ea, rowptr, fill, csr_src, ea_csr);
    k_aggr<<<(N_NODES+3)/4,256,0,stream>>>(xhb, as_, ad_, ea_csr, mebuf,
        rowptr, csr_src, bnA + l*128, bnS + l*128, h16, l);
  }

  k_tail<<<N_GRAPHS,128,0,stream>>>(h16, batch, gfin, gc_w, gc_b, gf1_w, gf1_b,
        gf2_w, gf2_b, p1_w, p1_b, p2_w, p2_b, p3_w, p3_b, out);
}